// Round 10
// baseline (330.454 us; speedup 1.0000x reference)
//
#include <hip/hip_runtime.h>
#include <stdint.h>

#define D_MODEL 1024
#define N_HEADS 16
#define DKH     64
#define D_FF    4096
#define BATCH   2
#define SEQ     2048
#define M_TOK   (BATCH*SEQ)   // 4096 tokens

typedef unsigned short u16;
typedef __attribute__((ext_vector_type(8))) short short8;   // 8 x bf16 = 4 VGPRs
typedef __attribute__((ext_vector_type(4))) float f32x4;

__device__ __forceinline__ u16 f2b(float f){
  union { float f; uint32_t i; } c; c.f = f;
  uint32_t x = c.i;
  uint32_t r = x + 0x7fffu + ((x >> 16) & 1u);   // RNE
  return (u16)(r >> 16);
}

// packed 2xfp32 -> 2xbf16 (RNE), single VALU op on gfx950
__device__ __forceinline__ uint32_t pk_bf16(float a, float b){
  uint32_t d;
  asm("v_cvt_pk_bf16_f32 %0, %1, %2" : "=v"(d) : "v"(a), "v"(b));
  return d;
}

// async global->LDS, 16B per lane; dest = wave-uniform base + lane*16
__device__ __forceinline__ void gl_lds16(const u16* g, u16* l){
  __builtin_amdgcn_global_load_lds(
      (const __attribute__((address_space(1))) void*)g,
      (__attribute__((address_space(3))) void*)l, 16, 0, 0);
}

#define MFMA16(a,b,c) __builtin_amdgcn_mfma_f32_16x16x32_bf16((a),(b),(c),0,0,0)

// ---------------------------------------------------------------------------
// Fused weight-cvt (6 matrices) + LN1 (y==6 slice).
// ---------------------------------------------------------------------------
__global__ __launch_bounds__(256) void cvt_ln_kernel(
    const float* __restrict__ s0, const float* __restrict__ s1,
    const float* __restrict__ s2, const float* __restrict__ s3,
    const float* __restrict__ s4, const float* __restrict__ s5,
    u16* __restrict__ d0, u16* __restrict__ d1, u16* __restrict__ d2,
    u16* __restrict__ d3, u16* __restrict__ d4, u16* __restrict__ d5,
    const float* __restrict__ X, const float* __restrict__ G,
    const float* __restrict__ Bt, u16* __restrict__ O)
{
  __shared__ float psum[4], psum2[4];
  if (blockIdx.y == 6){
    const int row = blockIdx.x;
    const int t = threadIdx.x;
    float4 xv = *(const float4*)&X[(size_t)row * D_MODEL + t * 4];
    float s  = xv.x + xv.y + xv.z + xv.w;
    float s2 = xv.x*xv.x + xv.y*xv.y + xv.z*xv.z + xv.w*xv.w;
    #pragma unroll
    for (int off = 32; off >= 1; off >>= 1){
      s  += __shfl_down(s,  off, 64);
      s2 += __shfl_down(s2, off, 64);
    }
    const int wv = t >> 6, ln = t & 63;
    if (ln == 0){ psum[wv] = s; psum2[wv] = s2; }
    __syncthreads();
    float ts  = psum[0] + psum[1] + psum[2] + psum[3];
    float ts2 = psum2[0] + psum2[1] + psum2[2] + psum2[3];
    float mean = ts * (1.f / D_MODEL);
    float var  = ts2 * (1.f / D_MODEL) - mean * mean;
    float rstd = rsqrtf(var + 1e-6f);
    float4 g4 = *(const float4*)&G[t * 4];
    float4 b4 = *(const float4*)&Bt[t * 4];
    ushort4 o;
    o.x = f2b(g4.x * (xv.x - mean) * rstd + b4.x);
    o.y = f2b(g4.y * (xv.y - mean) * rstd + b4.y);
    o.z = f2b(g4.z * (xv.z - mean) * rstd + b4.z);
    o.w = f2b(g4.w * (xv.w - mean) * rstd + b4.w);
    *(ushort4*)&O[(size_t)row * D_MODEL + t * 4] = o;
    return;
  }
  const float* s; u16* d; int n;
  switch (blockIdx.y){
    case 0: s=s0; d=d0; n=D_MODEL*D_MODEL; break;
    case 1: s=s1; d=d1; n=D_MODEL*D_MODEL; break;
    case 2: s=s2; d=d2; n=D_MODEL*D_MODEL; break;
    case 3: s=s3; d=d3; n=D_MODEL*D_MODEL; break;
    case 4: s=s4; d=d4; n=D_FF*D_MODEL;   break;
    default: s=s5; d=d5; n=D_MODEL*D_FF;  break;
  }
  int i = (blockIdx.x * 256 + threadIdx.x) * 4;
  if (i < n){
    float4 f = *(const float4*)&s[i];
    ushort4 o; o.x = f2b(f.x); o.y = f2b(f.y); o.z = f2b(f.z); o.w = f2b(f.w);
    *(ushort4*)&d[i] = o;
  }
}

// ---------------------------------------------------------------------------
// LayerNorm (standalone, for LN2): fp32 in, bf16 out.
// ---------------------------------------------------------------------------
__global__ __launch_bounds__(256) void ln_kernel(
    const float* __restrict__ X, const float* __restrict__ G,
    const float* __restrict__ Bt, u16* __restrict__ O)
{
  const int row = blockIdx.x;
  const int t = threadIdx.x;
  float4 xv = *(const float4*)&X[(size_t)row * D_MODEL + t * 4];
  float s  = xv.x + xv.y + xv.z + xv.w;
  float s2 = xv.x*xv.x + xv.y*xv.y + xv.z*xv.z + xv.w*xv.w;
  #pragma unroll
  for (int off = 32; off >= 1; off >>= 1){
    s  += __shfl_down(s,  off, 64);
    s2 += __shfl_down(s2, off, 64);
  }
  __shared__ float psum[4], psum2[4];
  const int wv = t >> 6, ln = t & 63;
  if (ln == 0){ psum[wv] = s; psum2[wv] = s2; }
  __syncthreads();
  float ts  = psum[0] + psum[1] + psum[2] + psum[3];
  float ts2 = psum2[0] + psum2[1] + psum2[2] + psum2[3];
  float mean = ts * (1.f / D_MODEL);
  float var  = ts2 * (1.f / D_MODEL) - mean * mean;
  float rstd = rsqrtf(var + 1e-6f);
  float4 g4 = *(const float4*)&G[t * 4];
  float4 b4 = *(const float4*)&Bt[t * 4];
  ushort4 o;
  o.x = f2b(g4.x * (xv.x - mean) * rstd + b4.x);
  o.y = f2b(g4.y * (xv.y - mean) * rstd + b4.y);
  o.z = f2b(g4.z * (xv.z - mean) * rstd + b4.z);
  o.w = f2b(g4.w * (xv.w - mean) * rstd + b4.w);
  *(ushort4*)&O[(size_t)row * D_MODEL + t * 4] = o;
}

// ---------------------------------------------------------------------------
// B^T GEMM core (device fn): TM x TN x BK tiles, 4 waves 2x2.
// m on blockIdx.x (XCD affinity). XOR-swizzled LDS + global_load_lds staging.
// EPI: 0=none, 1=GELU, 2=+resid. OUTF=1 -> fp32 out else bf16.
// Wrapped by distinct __global__ names (gemm_wo/ff1/ff2) for rocprof clarity.
// ---------------------------------------------------------------------------
template<int EPI, int OUTF, int TM, int TN, int BK>
__device__ __forceinline__ void gemm_core(
    const u16* __restrict__ A, const u16* __restrict__ W,
    const float* __restrict__ bias, const float* resid,
    void* Cout, int K, int Ndim)
{
  constexpr int MI = TM / 32;
  constexpr int NJ = TN / 32;
  constexpr int CPR = BK / 8;            // 16B chunks per LDS row
  constexpr int RPI = 512 / BK;          // rows covered per DMA instr
  constexpr int nAw = TM * BK / 512 / 4;
  constexpr int nBw = TN * BK / 512 / 4;
  __shared__ __align__(16) u16 sA[TM*BK];
  __shared__ __align__(16) u16 sB[TN*BK];
  const int t = threadIdx.x;
  const int w = t >> 6, lane = t & 63, lr = lane & 15, quad = lane >> 4;
  const int wm = (w & 1) * (TM/2), wn = (w >> 1) * (TN/2);
  const int m0 = blockIdx.x * TM, n0 = blockIdx.y * TN;
  const int sub = lane / CPR;
  const int cl  = lane % CPR;

  f32x4 acc[MI][NJ];
  #pragma unroll
  for (int i = 0; i < MI; i++)
    #pragma unroll
    for (int j = 0; j < NJ; j++) acc[i][j] = (f32x4){0.f,0.f,0.f,0.f};

  for (int k0 = 0; k0 < K; k0 += BK){
    __syncthreads();
    #pragma unroll
    for (int it = 0; it < nAw; it++){
      int R = (w*nAw + it) * RPI;
      int gr = R + sub;
      int gc = (cl ^ (gr & 7)) * 8;
      gl_lds16(&A[(size_t)(m0 + gr) * K + k0 + gc], &sA[R * BK]);
    }
    #pragma unroll
    for (int it = 0; it < nBw; it++){
      int R = (w*nBw + it) * RPI;
      int gr = R + sub;
      int gc = (cl ^ (gr & 7)) * 8;
      gl_lds16(&W[(size_t)(n0 + gr) * K + k0 + gc], &sB[R * BK]);
    }
    __syncthreads();
    #pragma unroll
    for (int ks = 0; ks < BK/32; ks++){
      short8 af[MI], bfr[NJ];
      #pragma unroll
      for (int i = 0; i < MI; i++)
        af[i]  = *(const short8*)&sA[(wm + i*16 + lr)*BK + (((ks*4 + quad) ^ (lr & 7)) * 8)];
      #pragma unroll
      for (int j = 0; j < NJ; j++)
        bfr[j] = *(const short8*)&sB[(wn + j*16 + lr)*BK + (((ks*4 + quad) ^ (lr & 7)) * 8)];
      #pragma unroll
      for (int i = 0; i < MI; i++)
        #pragma unroll
        for (int j = 0; j < NJ; j++)
          acc[i][j] = MFMA16(af[i], bfr[j], acc[i][j]);
    }
  }

  #pragma unroll
  for (int j = 0; j < NJ; j++){
    int gn = n0 + wn + j*16 + lr;
    float bb = bias[gn];
    #pragma unroll
    for (int i = 0; i < MI; i++){
      #pragma unroll
      for (int r = 0; r < 4; r++){
        int gm = m0 + wm + i*16 + quad*4 + r;   // C/D: row=quad*4+reg, col=lane&15
        size_t idx = (size_t)gm * Ndim + gn;
        float v = acc[i][j][r] + bb;
        if (EPI == 1){
          float p = v * (1.59576912f + 0.07135481f * v * v);
          float e = __builtin_amdgcn_exp2f(-1.44269504f * p);
          v = v * __builtin_amdgcn_rcpf(1.f + e);
        }
        if (EPI == 2) v += resid[idx];
        if (OUTF) ((float*)Cout)[idx] = v;
        else      ((u16*)Cout)[idx] = f2b(v);
      }
    }
  }
}

__global__ __launch_bounds__(256,2) void gemm_wo(
    const u16* __restrict__ A, const u16* __restrict__ W,
    const float* __restrict__ bias, const float* resid, void* Cout)
{ gemm_core<2,1,64,128,128>(A, W, bias, resid, Cout, D_MODEL, D_MODEL); }

__global__ __launch_bounds__(256,2) void gemm_ff1(
    const u16* __restrict__ A, const u16* __restrict__ W,
    const float* __restrict__ bias, void* Cout)
{ gemm_core<1,0,128,128,64>(A, W, bias, nullptr, Cout, D_MODEL, D_FF); }

__global__ __launch_bounds__(256,2) void gemm_ff2(
    const u16* __restrict__ A, const u16* __restrict__ W,
    const float* __restrict__ bias, const float* resid, void* Cout)
{ gemm_core<2,1,64,128,128>(A, W, bias, resid, Cout, D_FF, D_MODEL); }

// ---------------------------------------------------------------------------
// QKV GEMM: 128x128 tile, wave 64x64, BK=64, grid (32, 8, 3). z selects
// {Q,K,V}. Q pre-scaled by 0.125*log2(e). V (z==2) written TRANSPOSED to vt.
// ---------------------------------------------------------------------------
__global__ __launch_bounds__(256,2) void gemm_qkv(
    const u16* __restrict__ A,
    const u16* __restrict__ Wq, const float* __restrict__ bq,
    const u16* __restrict__ Wk, const float* __restrict__ bk,
    const u16* __restrict__ Wv, const float* __restrict__ bv,
    u16* __restrict__ Qo, u16* __restrict__ Ko, u16* __restrict__ Vo)
{
  __shared__ __align__(16) u16 smem[2*128*64];   // sA | sB; reused for V-transpose
  u16* sA = smem;
  u16* sB = smem + 128*64;
  const u16* W; const float* bias; float scale;
  if (blockIdx.z == 0){ W = Wq; bias = bq; scale = 0.125f * 1.44269504f; }
  else if (blockIdx.z == 1){ W = Wk; bias = bk; scale = 1.f; }
  else { W = Wv; bias = bv; scale = 1.f; }

  const int t = threadIdx.x;
  const int w = t >> 6, lane = t & 63, lr = lane & 15, quad = lane >> 4;
  const int wm = (w & 1) * 64, wn = (w >> 1) * 64;
  const int m0 = blockIdx.x * 128, n0 = blockIdx.y * 128;
  const int srow = lane >> 3;
  const int scol = ((lane & 7) ^ srow) * 8;
  const int K = D_MODEL;

  f32x4 acc[4][4];
  #pragma unroll
  for (int i = 0; i < 4; i++)
    #pragma unroll
    for (int j = 0; j < 4; j++) acc[i][j] = (f32x4){0.f,0.f,0.f,0.f};

  for (int k0 = 0; k0 < K; k0 += 64){
    __syncthreads();
    #pragma unroll
    for (int it = 0; it < 4; it++){
      gl_lds16(&A[(size_t)(m0 + it*32 + w*8 + srow) * K + k0 + scol], &sA[(it*32 + w*8) * 64]);
      gl_lds16(&W[(size_t)(n0 + it*32 + w*8 + srow) * K + k0 + scol], &sB[(it*32 + w*8) * 64]);
    }
    __syncthreads();
    #pragma unroll
    for (int ks = 0; ks < 2; ks++){
      short8 af[4], bfr[4];
      #pragma unroll
      for (int i = 0; i < 4; i++)
        af[i]  = *(const short8*)&sA[(wm + i*16 + lr)*64 + (((ks*4 + quad) ^ (lr & 7)) * 8)];
      #pragma unroll
      for (int j = 0; j < 4; j++)
        bfr[j] = *(const short8*)&sB[(wn + j*16 + lr)*64 + (((ks*4 + quad) ^ (lr & 7)) * 8)];
      #pragma unroll
      for (int i = 0; i < 4; i++)
        #pragma unroll
        for (int j = 0; j < 4; j++)
          acc[i][j] = MFMA16(af[i], bfr[j], acc[i][j]);
    }
  }

  if (blockIdx.z == 2){
    // --- V: transpose in LDS, write vt[BH][dk][SEQ] with b128 stores ---
    __syncthreads();   // all waves done reading sA/sB
    #pragma unroll
    for (int j = 0; j < 4; j++){
      int dl = wn + j*16 + lr;            // local dim 0..127
      float bb = bias[n0 + dl];
      #pragma unroll
      for (int i = 0; i < 4; i++){
        #pragma unroll
        for (int r = 0; r < 4; r++){
          int tok = wm + i*16 + quad*4 + r;   // local token 0..127
          int phys = (((tok >> 3) ^ (dl & 7)) * 8) + (tok & 7);
          smem[dl*128 + phys] = f2b(acc[i][j][r] + bb);
        }
      }
    }
    __syncthreads();
    const int b = m0 >> 11, sq0 = m0 & 2047, hh0 = n0 >> 6;
    #pragma unroll
    for (int it = 0; it < 8; it++){
      int idx = it*256 + t;
      int drow = idx >> 4, c = idx & 15;
      float4 val = *(const float4*)&smem[drow*128 + ((c ^ (drow & 7)) * 8)];
      int hh = hh0 + (drow >> 6), d = drow & 63;
      *(float4*)&Vo[(((size_t)(b*N_HEADS + hh))*DKH + d)*SEQ + sq0 + c*8] = val;
    }
    return;
  }

  u16* out = (blockIdx.z == 0) ? Qo : Ko;
  #pragma unroll
  for (int j = 0; j < 4; j++){
    int gn = n0 + wn + j*16 + lr;
    int hh = gn >> 6, d = gn & 63;
    float bb = bias[gn];
    #pragma unroll
    for (int i = 0; i < 4; i++){
      #pragma unroll
      for (int r = 0; r < 4; r++){
        int gm = m0 + wm + i*16 + quad*4 + r;
        int b = gm >> 11, sq = gm & 2047;
        float v = (acc[i][j][r] + bb) * scale;
        out[(((size_t)(b * N_HEADS + hh)) * SEQ + sq) * DKH + d] = f2b(v);
      }
    }
  }
}

// ---------------------------------------------------------------------------
// Flash attention, max-free. 256 threads = 4 waves x 32 q-rows (S^T
// reads/MFMA 0.5 vs 1.0 at 16q — halves LDS traffic per unit work).
// bh on blockIdx.x (KV L2 affinity). gl_lds16 swizzled staging; swizzled sP.
// LDS: sK 16K + sVt 16K + sP 32K = 64 KB -> 2 blocks/CU = 8 waves/CU.
// ---------------------------------------------------------------------------
__global__ __launch_bounds__(256,2) void attn_kernel(
    const u16* __restrict__ Q, const u16* __restrict__ K,
    const u16* __restrict__ Vt, u16* __restrict__ ctx)
{
  __shared__ __align__(16) u16 sK[128*64];
  __shared__ __align__(16) u16 sVt[64*128];
  __shared__ __align__(16) u16 sP[4*32*128];   // per-wave 32 q x 128 kv

  const int t = threadIdx.x, w = t >> 6, lane = t & 63;
  const int lr = lane & 15, quad = lane >> 4;
  const int bh = blockIdx.x;
  const int q0 = blockIdx.y * 128;
  const u16* Qp = Q + ((size_t)bh * SEQ + q0) * DKH;
  const u16* Kp = K + (size_t)bh * SEQ * DKH;
  const u16* Vp = Vt + (size_t)bh * DKH * SEQ;

  // Q fragments (B-operand), wave owns q rows w*32..w*32+31
  short8 qf[2][2];
  #pragma unroll
  for (int i = 0; i < 2; i++)
    #pragma unroll
    for (int ks = 0; ks < 2; ks++)
      qf[i][ks] = *(const short8*)&Qp[(size_t)(w*32 + i*16 + lr) * DKH + ks*32 + quad*8];

  short8 ones;
  #pragma unroll
  for (int e = 0; e < 8; e++) ones[e] = (short)0x3F80;

  f32x4 acco[2][4];   // ctx: q=i*16+quad*4+r, d=jc*16+lr
  f32x4 accl[2];      // l:   q=i*16+quad*4+r
  #pragma unroll
  for (int i = 0; i < 2; i++){
    accl[i] = (f32x4){0.f,0.f,0.f,0.f};
    #pragma unroll
    for (int jc = 0; jc < 4; jc++) acco[i][jc] = (f32x4){0.f,0.f,0.f,0.f};
  }

  for (int kt = 0; kt < SEQ/128; kt++){
    const int s0 = kt * 128;
    __syncthreads();
    #pragma unroll
    for (int it = 0; it < 4; it++){     // K tile 128 x 64 (8 rows/instr)
      int R = (w*4 + it) * 8;
      int gr = R + (lane >> 3);
      int gc = ((lane & 7) ^ (gr & 7)) * 8;
      gl_lds16(&Kp[(size_t)(s0 + gr) * DKH + gc], &sK[R * 64]);
    }
    #pragma unroll
    for (int it = 0; it < 4; it++){     // Vt tile 64 x 128 (4 rows/instr)
      int R = (w*4 + it) * 4;
      int gr = R + (lane >> 4);
      int gc = ((lane & 15) ^ (gr & 7)) * 8;
      gl_lds16(&Vp[(size_t)gr * SEQ + s0 + gc], &sVt[R * 128]);
    }
    __syncthreads();

    // S^T: A=K rows (kv), B=Q rows (q). D[kv=j*16+quad*4+r][q=i*16+lr]
    f32x4 st_[2][8];
    #pragma unroll
    for (int i = 0; i < 2; i++)
      #pragma unroll
      for (int j = 0; j < 8; j++) st_[i][j] = (f32x4){0.f,0.f,0.f,0.f};
    #pragma unroll
    for (int ks = 0; ks < 2; ks++){
      #pragma unroll
      for (int j = 0; j < 8; j++){
        short8 kf = *(const short8*)&sK[(j*16 + lr)*64 + (((ks*4 + quad) ^ (lr & 7)) * 8)];
        st_[0][j] = MFMA16(kf, qf[0][ks], st_[0][j]);
        st_[1][j] = MFMA16(kf, qf[1][ks], st_[1][j]);
      }
    }

    // P = 2^(S^T), pack pairs, b64 to swizzled per-wave sP[q][kv]
    #pragma unroll
    for (int i = 0; i < 2; i++)
      #pragma unroll
      for (int j = 0; j < 8; j++){
        float p0 = __builtin_amdgcn_exp2f(st_[i][j][0]);
        float p1 = __builtin_amdgcn_exp2f(st_[i][j][1]);
        float p2 = __builtin_amdgcn_exp2f(st_[i][j][2]);
        float p3 = __builtin_amdgcn_exp2f(st_[i][j][3]);
        uint2 pv; pv.x = pk_bf16(p0, p1); pv.y = pk_bf16(p2, p3);
        int c = j*2 + (quad >> 1);                 // logical kv chunk
        *(uint2*)&sP[w*4096 + (i*16 + lr)*128 + ((c ^ (lr & 7)) * 8) + (quad & 1)*4] = pv;
      }

    // PV + l: A=P rows (q), B=Vt rows (d) / ones
    #pragma unroll
    for (int ks = 0; ks < 4; ks++){
      short8 pf0 = *(const short8*)&sP[w*4096 + lr*128        + (((ks*4 + quad) ^ (lr & 7)) * 8)];
      short8 pf1 = *(const short8*)&sP[w*4096 + (16 + lr)*128 + (((ks*4 + quad) ^ (lr & 7)) * 8)];
      accl[0] = MFMA16(pf0, ones, accl[0]);
      accl[1] = MFMA16(pf1, ones, accl[1]);
      #pragma unroll
      for (int jc = 0; jc < 4; jc++){
        short8 vf = *(const short8*)&sVt[(jc*16 + lr)*128 + (((ks*4 + quad) ^ (lr & 7)) * 8)];
        acco[0][jc] = MFMA16(pf0, vf, acco[0][jc]);
        acco[1][jc] = MFMA16(pf1, vf, acco[1][jc]);
      }
    }
  }

  // epilogue: normalize by l, scatter to [B,S,H*dk]
  const int bq = bh >> 4, hh = bh & 15;
  u16* op = ctx + ((size_t)bq * SEQ + q0) * D_MODEL + hh * DKH;
  #pragma unroll
  for (int i = 0; i < 2; i++){
    #pragma unroll
    for (int r = 0; r < 4; r++){
      float rl = 1.f / accl[i][r];
      int row = w*32 + i*16 + quad*4 + r;
      #pragma unroll
      for (int jc = 0; jc < 4; jc++)
        op[(size_t)row * D_MODEL + jc*16 + lr] = f2b(acco[i][jc][r] * rl);
    }
  }
}

// ---------------------------------------------------------------------------
extern "C" void kernel_launch(void* const* d_in, const int* in_sizes, int n_in,
                              void* d_out, int out_size, void* d_ws, size_t ws_size,
                              hipStream_t stream)
{
  const float* x   = (const float*)d_in[0];
  const float* Wq  = (const float*)d_in[1];
  const float* bq  = (const float*)d_in[2];
  const float* Wk  = (const float*)d_in[3];
  const float* bk  = (const float*)d_in[4];
  const float* Wv  = (const float*)d_in[5];
  const float* bv  = (const float*)d_in[6];
  const float* Wo  = (const float*)d_in[7];
  const float* bo  = (const float*)d_in[8];
  const float* W1  = (const float*)d_in[9];
  const float* b1  = (const float*)d_in[10];
  const float* W2  = (const float*)d_in[11];
  const float* b2  = (const float*)d_in[12];
  const float* g1  = (const float*)d_in[13];
  const float* be1 = (const float*)d_in[14];
  const float* g2  = (const float*)d_in[15];
  const float* be2 = (const float*)d_in[16];

  char* ws = (char*)d_ws;
  const size_t MB = 1024ull * 1024ull;
  u16* wqb = (u16*)(ws + 0*MB);
  u16* wkb = (u16*)(ws + 2*MB);
  u16* wvb = (u16*)(ws + 4*MB);
  u16* wob = (u16*)(ws + 6*MB);
  u16* w1b = (u16*)(ws + 8*MB);    // 8 MB (4096x1024)
  u16* w2b = (u16*)(ws + 16*MB);   // 8 MB (1024x4096)
  u16* h   = (u16*)(ws + 24*MB);   // bf16 activations; reused as h2
  u16* q   = (u16*)(ws + 32*MB);   // [B,H,S,dk]
  u16* k   = (u16*)(ws + 40*MB);
  u16* ctx = (u16*)(ws + 48*MB);   // attn output
  u16* vt  = (u16*)(ws + 56*MB);   // [B,H,dk,S] — written by gemm_qkv z==2
  u16* ff  = (u16*)(ws + 32*MB);   // 32 MB [M,D_FF]; q/k/ctx/vt dead by then
  u16* h2  = h;
  float* x1 = (float*)d_out;       // attn residual output (fp32) in d_out

  // 0. weights -> bf16 + LN1 fused (7th y-slice)
  cvt_ln_kernel<<<dim3(4096, 7), 256, 0, stream>>>(
      Wq, Wk, Wv, Wo, W1, W2, wqb, wkb, wvb, wob, w1b, w2b,
      x, g1, be1, h);

  // 1. QKV projections (128x128, wave 64x64); V written transposed to vt
  gemm_qkv<<<dim3(M_TOK/128, D_MODEL/128, 3), 256, 0, stream>>>(
      h, wqb, bq, wkb, bk, wvb, bv, q, k, vt);
  // 2. flash attention (256 threads, 4 waves x 32 q)
  attn_kernel<<<dim3(BATCH*N_HEADS, SEQ/128), 256, 0, stream>>>(q, k, vt, ctx);
  // 3. Wo + residual(x) -> x1 fp32; 64x128 BK=128, grid 512
  gemm_wo<<<dim3(M_TOK/64, D_MODEL/128), 256, 0, stream>>>(
      ctx, wob, bo, x, (void*)x1);
  // 4. LN2 (fp32 x1 -> bf16 h2)
  ln_kernel<<<M_TOK, 256, 0, stream>>>(x1, g2, be2, h2);
  // 5. FF1 + GELU -> bf16 ff; 128x128 BK=64
  gemm_ff1<<<dim3(M_TOK/128, D_FF/128), 256, 0, stream>>>(
      h2, w1b, b1, (void*)ff);
  // 6. FF2 + residual(x1) -> d_out fp32; 64x128 BK=128
  gemm_ff2<<<dim3(M_TOK/64, D_MODEL/128), 256, 0, stream>>>(
      ff, w2b, b2, x1, d_out);
}

// Round 11
// 328.279 us; speedup vs baseline: 1.0066x; 1.0066x over previous
//
#include <hip/hip_runtime.h>
#include <stdint.h>

#define D_MODEL 1024
#define N_HEADS 16
#define DKH     64
#define D_FF    4096
#define BATCH   2
#define SEQ     2048
#define M_TOK   (BATCH*SEQ)   // 4096 tokens

typedef unsigned short u16;
typedef __attribute__((ext_vector_type(8))) short short8;   // 8 x bf16 = 4 VGPRs
typedef __attribute__((ext_vector_type(4))) float f32x4;

__device__ __forceinline__ u16 f2b(float f){
  union { float f; uint32_t i; } c; c.f = f;
  uint32_t x = c.i;
  uint32_t r = x + 0x7fffu + ((x >> 16) & 1u);   // RNE
  return (u16)(r >> 16);
}

// packed 2xfp32 -> 2xbf16 (RNE), single VALU op on gfx950
__device__ __forceinline__ uint32_t pk_bf16(float a, float b){
  uint32_t d;
  asm("v_cvt_pk_bf16_f32 %0, %1, %2" : "=v"(d) : "v"(a), "v"(b));
  return d;
}

// async global->LDS, 16B per lane; dest = wave-uniform base + lane*16
__device__ __forceinline__ void gl_lds16(const u16* g, u16* l){
  __builtin_amdgcn_global_load_lds(
      (const __attribute__((address_space(1))) void*)g,
      (__attribute__((address_space(3))) void*)l, 16, 0, 0);
}

#define MFMA16(a,b,c) __builtin_amdgcn_mfma_f32_16x16x32_bf16((a),(b),(c),0,0,0)

// ---------------------------------------------------------------------------
// Fused weight-cvt (6 matrices) + LN1 (y==6 slice).
// ---------------------------------------------------------------------------
__global__ __launch_bounds__(256) void cvt_ln_kernel(
    const float* __restrict__ s0, const float* __restrict__ s1,
    const float* __restrict__ s2, const float* __restrict__ s3,
    const float* __restrict__ s4, const float* __restrict__ s5,
    u16* __restrict__ d0, u16* __restrict__ d1, u16* __restrict__ d2,
    u16* __restrict__ d3, u16* __restrict__ d4, u16* __restrict__ d5,
    const float* __restrict__ X, const float* __restrict__ G,
    const float* __restrict__ Bt, u16* __restrict__ O)
{
  __shared__ float psum[4], psum2[4];
  if (blockIdx.y == 6){
    const int row = blockIdx.x;
    const int t = threadIdx.x;
    float4 xv = *(const float4*)&X[(size_t)row * D_MODEL + t * 4];
    float s  = xv.x + xv.y + xv.z + xv.w;
    float s2 = xv.x*xv.x + xv.y*xv.y + xv.z*xv.z + xv.w*xv.w;
    #pragma unroll
    for (int off = 32; off >= 1; off >>= 1){
      s  += __shfl_down(s,  off, 64);
      s2 += __shfl_down(s2, off, 64);
    }
    const int wv = t >> 6, ln = t & 63;
    if (ln == 0){ psum[wv] = s; psum2[wv] = s2; }
    __syncthreads();
    float ts  = psum[0] + psum[1] + psum[2] + psum[3];
    float ts2 = psum2[0] + psum2[1] + psum2[2] + psum2[3];
    float mean = ts * (1.f / D_MODEL);
    float var  = ts2 * (1.f / D_MODEL) - mean * mean;
    float rstd = rsqrtf(var + 1e-6f);
    float4 g4 = *(const float4*)&G[t * 4];
    float4 b4 = *(const float4*)&Bt[t * 4];
    ushort4 o;
    o.x = f2b(g4.x * (xv.x - mean) * rstd + b4.x);
    o.y = f2b(g4.y * (xv.y - mean) * rstd + b4.y);
    o.z = f2b(g4.z * (xv.z - mean) * rstd + b4.z);
    o.w = f2b(g4.w * (xv.w - mean) * rstd + b4.w);
    *(ushort4*)&O[(size_t)row * D_MODEL + t * 4] = o;
    return;
  }
  const float* s; u16* d; int n;
  switch (blockIdx.y){
    case 0: s=s0; d=d0; n=D_MODEL*D_MODEL; break;
    case 1: s=s1; d=d1; n=D_MODEL*D_MODEL; break;
    case 2: s=s2; d=d2; n=D_MODEL*D_MODEL; break;
    case 3: s=s3; d=d3; n=D_MODEL*D_MODEL; break;
    case 4: s=s4; d=d4; n=D_FF*D_MODEL;   break;
    default: s=s5; d=d5; n=D_MODEL*D_FF;  break;
  }
  int i = (blockIdx.x * 256 + threadIdx.x) * 4;
  if (i < n){
    float4 f = *(const float4*)&s[i];
    ushort4 o; o.x = f2b(f.x); o.y = f2b(f.y); o.z = f2b(f.z); o.w = f2b(f.w);
    *(ushort4*)&d[i] = o;
  }
}

// ---------------------------------------------------------------------------
// LayerNorm (standalone, for LN2): fp32 in, bf16 out.
// ---------------------------------------------------------------------------
__global__ __launch_bounds__(256) void ln_kernel(
    const float* __restrict__ X, const float* __restrict__ G,
    const float* __restrict__ Bt, u16* __restrict__ O)
{
  const int row = blockIdx.x;
  const int t = threadIdx.x;
  float4 xv = *(const float4*)&X[(size_t)row * D_MODEL + t * 4];
  float s  = xv.x + xv.y + xv.z + xv.w;
  float s2 = xv.x*xv.x + xv.y*xv.y + xv.z*xv.z + xv.w*xv.w;
  #pragma unroll
  for (int off = 32; off >= 1; off >>= 1){
    s  += __shfl_down(s,  off, 64);
    s2 += __shfl_down(s2, off, 64);
  }
  __shared__ float psum[4], psum2[4];
  const int wv = t >> 6, ln = t & 63;
  if (ln == 0){ psum[wv] = s; psum2[wv] = s2; }
  __syncthreads();
  float ts  = psum[0] + psum[1] + psum[2] + psum[3];
  float ts2 = psum2[0] + psum2[1] + psum2[2] + psum2[3];
  float mean = ts * (1.f / D_MODEL);
  float var  = ts2 * (1.f / D_MODEL) - mean * mean;
  float rstd = rsqrtf(var + 1e-6f);
  float4 g4 = *(const float4*)&G[t * 4];
  float4 b4 = *(const float4*)&Bt[t * 4];
  ushort4 o;
  o.x = f2b(g4.x * (xv.x - mean) * rstd + b4.x);
  o.y = f2b(g4.y * (xv.y - mean) * rstd + b4.y);
  o.z = f2b(g4.z * (xv.z - mean) * rstd + b4.z);
  o.w = f2b(g4.w * (xv.w - mean) * rstd + b4.w);
  *(ushort4*)&O[(size_t)row * D_MODEL + t * 4] = o;
}

// ---------------------------------------------------------------------------
// Double-buffered single-barrier GEMM core (AITER-style pipeline):
// per iter: s_waitcnt vmcnt(0) [only tile-k loads outstanding; k+1 not yet
// issued] -> raw s_barrier -> issue DMA(k+1) into other buffer -> MFMA on k.
// DMA(k+1) stays in flight across the whole compute phase; one barrier/iter.
// BK=64 (conflict-free swizzle), dbuf LDS = (TM+TN)*64*2*2B.
// ---------------------------------------------------------------------------
template<int EPI, int OUTF, int TM, int TN>
__device__ __forceinline__ void gemm_core_db(
    const u16* __restrict__ A, const u16* __restrict__ W,
    const float* __restrict__ bias, const float* resid,
    void* Cout, int K, int Ndim)
{
  constexpr int BK = 64;
  constexpr int MI = TM / 32;
  constexpr int NJ = TN / 32;
  constexpr int nAw = TM * BK / 2048;    // A staging instrs per wave
  constexpr int nBw = TN * BK / 2048;
  __shared__ __align__(16) u16 sA[2][TM*BK];
  __shared__ __align__(16) u16 sB[2][TN*BK];
  const int t = threadIdx.x;
  const int w = t >> 6, lane = t & 63, lr = lane & 15, quad = lane >> 4;
  const int wm = (w & 1) * (TM/2), wn = (w >> 1) * (TN/2);
  const int m0 = blockIdx.x * TM, n0 = blockIdx.y * TN;
  const int sub = lane >> 3;             // CPR=8
  const int cl  = lane & 7;

  f32x4 acc[MI][NJ];
  #pragma unroll
  for (int i = 0; i < MI; i++)
    #pragma unroll
    for (int j = 0; j < NJ; j++) acc[i][j] = (f32x4){0.f,0.f,0.f,0.f};

  auto load_tile = [&](int k0, int buf){
    #pragma unroll
    for (int it = 0; it < nAw; it++){
      int R = (w*nAw + it) * 8;
      int gr = R + sub;
      int gc = (cl ^ (gr & 7)) * 8;
      gl_lds16(&A[(size_t)(m0 + gr) * K + k0 + gc], &sA[buf][R * BK]);
    }
    #pragma unroll
    for (int it = 0; it < nBw; it++){
      int R = (w*nBw + it) * 8;
      int gr = R + sub;
      int gc = (cl ^ (gr & 7)) * 8;
      gl_lds16(&W[(size_t)(n0 + gr) * K + k0 + gc], &sB[buf][R * BK]);
    }
  };

  load_tile(0, 0);
  const int iters = K / BK;
  for (int it = 0; it < iters; it++){
    const int cur = it & 1;
    // my tile-it loads done (tile-it+1 not yet issued -> not drained here)
    asm volatile("s_waitcnt vmcnt(0)" ::: "memory");
    asm volatile("s_barrier" ::: "memory");   // all waves' loads(it) visible
    if (it + 1 < iters) load_tile((it + 1) * BK, cur ^ 1);
    #pragma unroll
    for (int ks = 0; ks < 2; ks++){
      short8 af[MI], bfr[NJ];
      #pragma unroll
      for (int i = 0; i < MI; i++)
        af[i]  = *(const short8*)&sA[cur][(wm + i*16 + lr)*BK + (((ks*4 + quad) ^ (lr & 7)) * 8)];
      #pragma unroll
      for (int j = 0; j < NJ; j++)
        bfr[j] = *(const short8*)&sB[cur][(wn + j*16 + lr)*BK + (((ks*4 + quad) ^ (lr & 7)) * 8)];
      #pragma unroll
      for (int i = 0; i < MI; i++)
        #pragma unroll
        for (int j = 0; j < NJ; j++)
          acc[i][j] = MFMA16(af[i], bfr[j], acc[i][j]);
    }
  }

  #pragma unroll
  for (int j = 0; j < NJ; j++){
    int gn = n0 + wn + j*16 + lr;
    float bb = bias[gn];
    #pragma unroll
    for (int i = 0; i < MI; i++){
      #pragma unroll
      for (int r = 0; r < 4; r++){
        int gm = m0 + wm + i*16 + quad*4 + r;   // C/D: row=quad*4+reg, col=lane&15
        size_t idx = (size_t)gm * Ndim + gn;
        float v = acc[i][j][r] + bb;
        if (EPI == 1){
          float p = v * (1.59576912f + 0.07135481f * v * v);
          float e = __builtin_amdgcn_exp2f(-1.44269504f * p);
          v = v * __builtin_amdgcn_rcpf(1.f + e);
        }
        if (EPI == 2) v += resid[idx];
        if (OUTF) ((float*)Cout)[idx] = v;
        else      ((u16*)Cout)[idx] = f2b(v);
      }
    }
  }
}

// ---------------------------------------------------------------------------
// Single-buffered core (proven) for FF1.
// ---------------------------------------------------------------------------
template<int EPI, int OUTF, int TM, int TN, int BK>
__device__ __forceinline__ void gemm_core(
    const u16* __restrict__ A, const u16* __restrict__ W,
    const float* __restrict__ bias, const float* resid,
    void* Cout, int K, int Ndim)
{
  constexpr int MI = TM / 32;
  constexpr int NJ = TN / 32;
  constexpr int CPR = BK / 8;
  constexpr int RPI = 512 / BK;
  constexpr int nAw = TM * BK / 512 / 4;
  constexpr int nBw = TN * BK / 512 / 4;
  __shared__ __align__(16) u16 sA[TM*BK];
  __shared__ __align__(16) u16 sB[TN*BK];
  const int t = threadIdx.x;
  const int w = t >> 6, lane = t & 63, lr = lane & 15, quad = lane >> 4;
  const int wm = (w & 1) * (TM/2), wn = (w >> 1) * (TN/2);
  const int m0 = blockIdx.x * TM, n0 = blockIdx.y * TN;
  const int sub = lane / CPR;
  const int cl  = lane % CPR;

  f32x4 acc[MI][NJ];
  #pragma unroll
  for (int i = 0; i < MI; i++)
    #pragma unroll
    for (int j = 0; j < NJ; j++) acc[i][j] = (f32x4){0.f,0.f,0.f,0.f};

  for (int k0 = 0; k0 < K; k0 += BK){
    __syncthreads();
    #pragma unroll
    for (int it = 0; it < nAw; it++){
      int R = (w*nAw + it) * RPI;
      int gr = R + sub;
      int gc = (cl ^ (gr & 7)) * 8;
      gl_lds16(&A[(size_t)(m0 + gr) * K + k0 + gc], &sA[R * BK]);
    }
    #pragma unroll
    for (int it = 0; it < nBw; it++){
      int R = (w*nBw + it) * RPI;
      int gr = R + sub;
      int gc = (cl ^ (gr & 7)) * 8;
      gl_lds16(&W[(size_t)(n0 + gr) * K + k0 + gc], &sB[R * BK]);
    }
    __syncthreads();
    #pragma unroll
    for (int ks = 0; ks < BK/32; ks++){
      short8 af[MI], bfr[NJ];
      #pragma unroll
      for (int i = 0; i < MI; i++)
        af[i]  = *(const short8*)&sA[(wm + i*16 + lr)*BK + (((ks*4 + quad) ^ (lr & 7)) * 8)];
      #pragma unroll
      for (int j = 0; j < NJ; j++)
        bfr[j] = *(const short8*)&sB[(wn + j*16 + lr)*BK + (((ks*4 + quad) ^ (lr & 7)) * 8)];
      #pragma unroll
      for (int i = 0; i < MI; i++)
        #pragma unroll
        for (int j = 0; j < NJ; j++)
          acc[i][j] = MFMA16(af[i], bfr[j], acc[i][j]);
    }
  }

  #pragma unroll
  for (int j = 0; j < NJ; j++){
    int gn = n0 + wn + j*16 + lr;
    float bb = bias[gn];
    #pragma unroll
    for (int i = 0; i < MI; i++){
      #pragma unroll
      for (int r = 0; r < 4; r++){
        int gm = m0 + wm + i*16 + quad*4 + r;
        size_t idx = (size_t)gm * Ndim + gn;
        float v = acc[i][j][r] + bb;
        if (EPI == 1){
          float p = v * (1.59576912f + 0.07135481f * v * v);
          float e = __builtin_amdgcn_exp2f(-1.44269504f * p);
          v = v * __builtin_amdgcn_rcpf(1.f + e);
        }
        if (EPI == 2) v += resid[idx];
        if (OUTF) ((float*)Cout)[idx] = v;
        else      ((u16*)Cout)[idx] = f2b(v);
      }
    }
  }
}

__global__ __launch_bounds__(256,2) void gemm_wo(
    const u16* __restrict__ A, const u16* __restrict__ W,
    const float* __restrict__ bias, const float* resid, void* Cout)
{ gemm_core_db<2,1,64,128>(A, W, bias, resid, Cout, D_MODEL, D_MODEL); }

__global__ __launch_bounds__(256,2) void gemm_ff1(
    const u16* __restrict__ A, const u16* __restrict__ W,
    const float* __restrict__ bias, void* Cout)
{ gemm_core<1,0,128,128,64>(A, W, bias, nullptr, Cout, D_MODEL, D_FF); }

__global__ __launch_bounds__(256,2) void gemm_ff2(
    const u16* __restrict__ A, const u16* __restrict__ W,
    const float* __restrict__ bias, const float* resid, void* Cout)
{ gemm_core_db<2,1,64,128>(A, W, bias, resid, Cout, D_FF, D_MODEL); }

// ---------------------------------------------------------------------------
// QKV GEMM: 128x128 tile, wave 64x64, BK=64, grid (32, 8, 3). z selects
// {Q,K,V}. Q pre-scaled by 0.125*log2(e). V (z==2) written TRANSPOSED to vt.
// ---------------------------------------------------------------------------
__global__ __launch_bounds__(256,2) void gemm_qkv(
    const u16* __restrict__ A,
    const u16* __restrict__ Wq, const float* __restrict__ bq,
    const u16* __restrict__ Wk, const float* __restrict__ bk,
    const u16* __restrict__ Wv, const float* __restrict__ bv,
    u16* __restrict__ Qo, u16* __restrict__ Ko, u16* __restrict__ Vo)
{
  __shared__ __align__(16) u16 smem[2*128*64];   // sA | sB; reused for V-transpose
  u16* sA = smem;
  u16* sB = smem + 128*64;
  const u16* W; const float* bias; float scale;
  if (blockIdx.z == 0){ W = Wq; bias = bq; scale = 0.125f * 1.44269504f; }
  else if (blockIdx.z == 1){ W = Wk; bias = bk; scale = 1.f; }
  else { W = Wv; bias = bv; scale = 1.f; }

  const int t = threadIdx.x;
  const int w = t >> 6, lane = t & 63, lr = lane & 15, quad = lane >> 4;
  const int wm = (w & 1) * 64, wn = (w >> 1) * 64;
  const int m0 = blockIdx.x * 128, n0 = blockIdx.y * 128;
  const int srow = lane >> 3;
  const int scol = ((lane & 7) ^ srow) * 8;
  const int K = D_MODEL;

  f32x4 acc[4][4];
  #pragma unroll
  for (int i = 0; i < 4; i++)
    #pragma unroll
    for (int j = 0; j < 4; j++) acc[i][j] = (f32x4){0.f,0.f,0.f,0.f};

  for (int k0 = 0; k0 < K; k0 += 64){
    __syncthreads();
    #pragma unroll
    for (int it = 0; it < 4; it++){
      gl_lds16(&A[(size_t)(m0 + it*32 + w*8 + srow) * K + k0 + scol], &sA[(it*32 + w*8) * 64]);
      gl_lds16(&W[(size_t)(n0 + it*32 + w*8 + srow) * K + k0 + scol], &sB[(it*32 + w*8) * 64]);
    }
    __syncthreads();
    #pragma unroll
    for (int ks = 0; ks < 2; ks++){
      short8 af[4], bfr[4];
      #pragma unroll
      for (int i = 0; i < 4; i++)
        af[i]  = *(const short8*)&sA[(wm + i*16 + lr)*64 + (((ks*4 + quad) ^ (lr & 7)) * 8)];
      #pragma unroll
      for (int j = 0; j < 4; j++)
        bfr[j] = *(const short8*)&sB[(wn + j*16 + lr)*64 + (((ks*4 + quad) ^ (lr & 7)) * 8)];
      #pragma unroll
      for (int i = 0; i < 4; i++)
        #pragma unroll
        for (int j = 0; j < 4; j++)
          acc[i][j] = MFMA16(af[i], bfr[j], acc[i][j]);
    }
  }

  if (blockIdx.z == 2){
    // --- V: transpose in LDS, write vt[BH][dk][SEQ] with b128 stores ---
    __syncthreads();   // all waves done reading sA/sB
    #pragma unroll
    for (int j = 0; j < 4; j++){
      int dl = wn + j*16 + lr;            // local dim 0..127
      float bb = bias[n0 + dl];
      #pragma unroll
      for (int i = 0; i < 4; i++){
        #pragma unroll
        for (int r = 0; r < 4; r++){
          int tok = wm + i*16 + quad*4 + r;   // local token 0..127
          int phys = (((tok >> 3) ^ (dl & 7)) * 8) + (tok & 7);
          smem[dl*128 + phys] = f2b(acc[i][j][r] + bb);
        }
      }
    }
    __syncthreads();
    const int b = m0 >> 11, sq0 = m0 & 2047, hh0 = n0 >> 6;
    #pragma unroll
    for (int it = 0; it < 8; it++){
      int idx = it*256 + t;
      int drow = idx >> 4, c = idx & 15;
      float4 val = *(const float4*)&smem[drow*128 + ((c ^ (drow & 7)) * 8)];
      int hh = hh0 + (drow >> 6), d = drow & 63;
      *(float4*)&Vo[(((size_t)(b*N_HEADS + hh))*DKH + d)*SEQ + sq0 + c*8] = val;
    }
    return;
  }

  u16* out = (blockIdx.z == 0) ? Qo : Ko;
  #pragma unroll
  for (int j = 0; j < 4; j++){
    int gn = n0 + wn + j*16 + lr;
    int hh = gn >> 6, d = gn & 63;
    float bb = bias[gn];
    #pragma unroll
    for (int i = 0; i < 4; i++){
      #pragma unroll
      for (int r = 0; r < 4; r++){
        int gm = m0 + wm + i*16 + quad*4 + r;
        int b = gm >> 11, sq = gm & 2047;
        float v = (acc[i][j][r] + bb) * scale;
        out[(((size_t)(b * N_HEADS + hh)) * SEQ + sq) * DKH + d] = f2b(v);
      }
    }
  }
}

// ---------------------------------------------------------------------------
// Flash attention (round-7 proven): 512 threads = 8 waves x 16 q-rows.
// bh on blockIdx.x. gl_lds16 swizzled staging; swizzled sP. LDS 64 KB.
// ---------------------------------------------------------------------------
__global__ __launch_bounds__(512,2) void attn_kernel(
    const u16* __restrict__ Q, const u16* __restrict__ K,
    const u16* __restrict__ Vt, u16* __restrict__ ctx)
{
  __shared__ __align__(16) u16 sK[128*64];
  __shared__ __align__(16) u16 sVt[64*128];
  __shared__ __align__(16) u16 sP[8*16*128];   // per-wave 16 q x 128 kv

  const int t = threadIdx.x, w = t >> 6, lane = t & 63;
  const int lr = lane & 15, quad = lane >> 4;
  const int bh = blockIdx.x;
  const int q0 = blockIdx.y * 128;
  const u16* Qp = Q + ((size_t)bh * SEQ + q0) * DKH;
  const u16* Kp = K + (size_t)bh * SEQ * DKH;
  const u16* Vp = Vt + (size_t)bh * DKH * SEQ;

  short8 qf[2];
  #pragma unroll
  for (int ks = 0; ks < 2; ks++)
    qf[ks] = *(const short8*)&Qp[(size_t)(w*16 + lr) * DKH + ks*32 + quad*8];

  short8 ones;
  #pragma unroll
  for (int e = 0; e < 8; e++) ones[e] = (short)0x3F80;

  f32x4 acco[4];   // ctx: q=quad*4+r, d=jc*16+lr
  f32x4 accl;      // l:   q=quad*4+r
  accl = (f32x4){0.f,0.f,0.f,0.f};
  #pragma unroll
  for (int jc = 0; jc < 4; jc++) acco[jc] = (f32x4){0.f,0.f,0.f,0.f};

  const int srow = lane >> 3;
  const int sc8  = ((lane & 7) ^ srow) * 8;
  const int lro  = lane >> 4, cl = lane & 15;

  for (int kt = 0; kt < SEQ/128; kt++){
    const int s0 = kt * 128;
    __syncthreads();
    #pragma unroll
    for (int it = 0; it < 2; it++)     // K tile 128 x 64
      gl_lds16(&Kp[(size_t)(s0 + it*64 + w*8 + srow) * DKH + sc8],
               &sK[(it*64 + w*8) * 64]);
    #pragma unroll
    for (int it = 0; it < 2; it++){    // Vt tile 64 x 128
      int R = w*8 + it*4;
      int gr = R + lro;
      int gc = (cl ^ (gr & 7)) * 8;
      gl_lds16(&Vp[(size_t)gr * SEQ + s0 + gc], &sVt[R * 128]);
    }
    __syncthreads();

    // S^T: A=K rows (kv), B=Q rows (q). D[kv=j*16+quad*4+r][q=lr]
    f32x4 st_[8];
    #pragma unroll
    for (int j = 0; j < 8; j++) st_[j] = (f32x4){0.f,0.f,0.f,0.f};
    #pragma unroll
    for (int ks = 0; ks < 2; ks++){
      #pragma unroll
      for (int j = 0; j < 8; j++){
        short8 kf = *(const short8*)&sK[(j*16 + lr)*64 + (((ks*4 + quad) ^ (lr & 7)) * 8)];
        st_[j] = MFMA16(kf, qf[ks], st_[j]);
      }
    }

    // P = 2^(S^T), pack pairs, b64 to swizzled sP[q=lr][kv]
    #pragma unroll
    for (int j = 0; j < 8; j++){
      float p0 = __builtin_amdgcn_exp2f(st_[j][0]);
      float p1 = __builtin_amdgcn_exp2f(st_[j][1]);
      float p2 = __builtin_amdgcn_exp2f(st_[j][2]);
      float p3 = __builtin_amdgcn_exp2f(st_[j][3]);
      uint2 pv; pv.x = pk_bf16(p0, p1); pv.y = pk_bf16(p2, p3);
      int c = j*2 + (quad >> 1);
      *(uint2*)&sP[w*2048 + lr*128 + ((c ^ (lr & 7)) * 8) + (quad & 1)*4] = pv;
    }

    // PV + l: A=P rows (q), B=Vt rows (d) / ones
    #pragma unroll
    for (int ks = 0; ks < 4; ks++){
      short8 pf = *(const short8*)&sP[w*2048 + lr*128 + (((ks*4 + quad) ^ (lr & 7)) * 8)];
      accl = MFMA16(pf, ones, accl);
      #pragma unroll
      for (int jc = 0; jc < 4; jc++){
        short8 vf = *(const short8*)&sVt[(jc*16 + lr)*128 + (((ks*4 + quad) ^ (lr & 7)) * 8)];
        acco[jc] = MFMA16(pf, vf, acco[jc]);
      }
    }
  }

  // epilogue: normalize by l, scatter to [B,S,H*dk]
  const int bq = bh >> 4, hh = bh & 15;
  u16* op = ctx + ((size_t)bq * SEQ + q0) * D_MODEL + hh * DKH;
  #pragma unroll
  for (int r = 0; r < 4; r++){
    float rl = 1.f / accl[r];
    int row = w*16 + quad*4 + r;
    #pragma unroll
    for (int jc = 0; jc < 4; jc++)
      op[(size_t)row * D_MODEL + jc*16 + lr] = f2b(acco[jc][r] * rl);
  }
}

// ---------------------------------------------------------------------------
extern "C" void kernel_launch(void* const* d_in, const int* in_sizes, int n_in,
                              void* d_out, int out_size, void* d_ws, size_t ws_size,
                              hipStream_t stream)
{
  const float* x   = (const float*)d_in[0];
  const float* Wq  = (const float*)d_in[1];
  const float* bq  = (const float*)d_in[2];
  const float* Wk  = (const float*)d_in[3];
  const float* bk  = (const float*)d_in[4];
  const float* Wv  = (const float*)d_in[5];
  const float* bv  = (const float*)d_in[6];
  const float* Wo  = (const float*)d_in[7];
  const float* bo  = (const float*)d_in[8];
  const float* W1  = (const float*)d_in[9];
  const float* b1  = (const float*)d_in[10];
  const float* W2  = (const float*)d_in[11];
  const float* b2  = (const float*)d_in[12];
  const float* g1  = (const float*)d_in[13];
  const float* be1 = (const float*)d_in[14];
  const float* g2  = (const float*)d_in[15];
  const float* be2 = (const float*)d_in[16];

  char* ws = (char*)d_ws;
  const size_t MB = 1024ull * 1024ull;
  u16* wqb = (u16*)(ws + 0*MB);
  u16* wkb = (u16*)(ws + 2*MB);
  u16* wvb = (u16*)(ws + 4*MB);
  u16* wob = (u16*)(ws + 6*MB);
  u16* w1b = (u16*)(ws + 8*MB);    // 8 MB (4096x1024)
  u16* w2b = (u16*)(ws + 16*MB);   // 8 MB (1024x4096)
  u16* h   = (u16*)(ws + 24*MB);   // bf16 activations; reused as h2
  u16* q   = (u16*)(ws + 32*MB);   // [B,H,S,dk]
  u16* k   = (u16*)(ws + 40*MB);
  u16* ctx = (u16*)(ws + 48*MB);   // attn output
  u16* vt  = (u16*)(ws + 56*MB);   // [B,H,dk,S] — written by gemm_qkv z==2
  u16* ff  = (u16*)(ws + 32*MB);   // 32 MB [M,D_FF]; q/k/ctx/vt dead by then
  u16* h2  = h;
  float* x1 = (float*)d_out;       // attn residual output (fp32) in d_out

  // 0. weights -> bf16 + LN1 fused (7th y-slice)
  cvt_ln_kernel<<<dim3(4096, 7), 256, 0, stream>>>(
      Wq, Wk, Wv, Wo, W1, W2, wqb, wkb, wvb, wob, w1b, w2b,
      x, g1, be1, h);

  // 1. QKV projections (128x128, wave 64x64); V written transposed to vt
  gemm_qkv<<<dim3(M_TOK/128, D_MODEL/128, 3), 256, 0, stream>>>(
      h, wqb, bq, wkb, bk, wvb, bv, q, k, vt);
  // 2. flash attention (512 threads, 8 waves)
  attn_kernel<<<dim3(BATCH*N_HEADS, SEQ/128), 512, 0, stream>>>(q, k, vt, ctx);
  // 3. Wo + residual(x) -> x1 fp32; dbuf pipeline, 64x128 BK=64
  gemm_wo<<<dim3(M_TOK/64, D_MODEL/128), 256, 0, stream>>>(
      ctx, wob, bo, x, (void*)x1);
  // 4. LN2 (fp32 x1 -> bf16 h2)
  ln_kernel<<<M_TOK, 256, 0, stream>>>(x1, g2, be2, h2);
  // 5. FF1 + GELU -> bf16 ff; 128x128 BK=64 single-buf
  gemm_ff1<<<dim3(M_TOK/128, D_FF/128), 256, 0, stream>>>(
      h2, w1b, b1, (void*)ff);
  // 6. FF2 + residual(x1) -> d_out fp32; dbuf pipeline, 64x128 BK=64
  gemm_ff2<<<dim3(M_TOK/64, D_MODEL/128), 256, 0, stream>>>(
      ff, w2b, b2, x1, d_out);
}

// Round 12
// 322.182 us; speedup vs baseline: 1.0257x; 1.0189x over previous
//
#include <hip/hip_runtime.h>
#include <stdint.h>

#define D_MODEL 1024
#define N_HEADS 16
#define DKH     64
#define D_FF    4096
#define BATCH   2
#define SEQ     2048
#define M_TOK   (BATCH*SEQ)   // 4096 tokens

typedef unsigned short u16;
typedef __attribute__((ext_vector_type(8))) short short8;   // 8 x bf16 = 4 VGPRs
typedef __attribute__((ext_vector_type(4))) float f32x4;

__device__ __forceinline__ u16 f2b(float f){
  union { float f; uint32_t i; } c; c.f = f;
  uint32_t x = c.i;
  uint32_t r = x + 0x7fffu + ((x >> 16) & 1u);   // RNE
  return (u16)(r >> 16);
}

// packed 2xfp32 -> 2xbf16 (RNE), single VALU op on gfx950
__device__ __forceinline__ uint32_t pk_bf16(float a, float b){
  uint32_t d;
  asm("v_cvt_pk_bf16_f32 %0, %1, %2" : "=v"(d) : "v"(a), "v"(b));
  return d;
}

// async global->LDS, 16B per lane; dest = wave-uniform base + lane*16
__device__ __forceinline__ void gl_lds16(const u16* g, u16* l){
  __builtin_amdgcn_global_load_lds(
      (const __attribute__((address_space(1))) void*)g,
      (__attribute__((address_space(3))) void*)l, 16, 0, 0);
}

#define MFMA16(a,b,c) __builtin_amdgcn_mfma_f32_16x16x32_bf16((a),(b),(c),0,0,0)

// ---------------------------------------------------------------------------
// Fused weight-cvt (6 matrices) + LN1 (y==6 slice).
// ---------------------------------------------------------------------------
__global__ __launch_bounds__(256) void cvt_ln_kernel(
    const float* __restrict__ s0, const float* __restrict__ s1,
    const float* __restrict__ s2, const float* __restrict__ s3,
    const float* __restrict__ s4, const float* __restrict__ s5,
    u16* __restrict__ d0, u16* __restrict__ d1, u16* __restrict__ d2,
    u16* __restrict__ d3, u16* __restrict__ d4, u16* __restrict__ d5,
    const float* __restrict__ X, const float* __restrict__ G,
    const float* __restrict__ Bt, u16* __restrict__ O)
{
  __shared__ float psum[4], psum2[4];
  if (blockIdx.y == 6){
    const int row = blockIdx.x;
    const int t = threadIdx.x;
    float4 xv = *(const float4*)&X[(size_t)row * D_MODEL + t * 4];
    float s  = xv.x + xv.y + xv.z + xv.w;
    float s2 = xv.x*xv.x + xv.y*xv.y + xv.z*xv.z + xv.w*xv.w;
    #pragma unroll
    for (int off = 32; off >= 1; off >>= 1){
      s  += __shfl_down(s,  off, 64);
      s2 += __shfl_down(s2, off, 64);
    }
    const int wv = t >> 6, ln = t & 63;
    if (ln == 0){ psum[wv] = s; psum2[wv] = s2; }
    __syncthreads();
    float ts  = psum[0] + psum[1] + psum[2] + psum[3];
    float ts2 = psum2[0] + psum2[1] + psum2[2] + psum2[3];
    float mean = ts * (1.f / D_MODEL);
    float var  = ts2 * (1.f / D_MODEL) - mean * mean;
    float rstd = rsqrtf(var + 1e-6f);
    float4 g4 = *(const float4*)&G[t * 4];
    float4 b4 = *(const float4*)&Bt[t * 4];
    ushort4 o;
    o.x = f2b(g4.x * (xv.x - mean) * rstd + b4.x);
    o.y = f2b(g4.y * (xv.y - mean) * rstd + b4.y);
    o.z = f2b(g4.z * (xv.z - mean) * rstd + b4.z);
    o.w = f2b(g4.w * (xv.w - mean) * rstd + b4.w);
    *(ushort4*)&O[(size_t)row * D_MODEL + t * 4] = o;
    return;
  }
  const float* s; u16* d; int n;
  switch (blockIdx.y){
    case 0: s=s0; d=d0; n=D_MODEL*D_MODEL; break;
    case 1: s=s1; d=d1; n=D_MODEL*D_MODEL; break;
    case 2: s=s2; d=d2; n=D_MODEL*D_MODEL; break;
    case 3: s=s3; d=d3; n=D_MODEL*D_MODEL; break;
    case 4: s=s4; d=d4; n=D_FF*D_MODEL;   break;
    default: s=s5; d=d5; n=D_MODEL*D_FF;  break;
  }
  int i = (blockIdx.x * 256 + threadIdx.x) * 4;
  if (i < n){
    float4 f = *(const float4*)&s[i];
    ushort4 o; o.x = f2b(f.x); o.y = f2b(f.y); o.z = f2b(f.z); o.w = f2b(f.w);
    *(ushort4*)&d[i] = o;
  }
}

// ---------------------------------------------------------------------------
// LayerNorm (standalone, for LN2): fp32 in, bf16 out.
// ---------------------------------------------------------------------------
__global__ __launch_bounds__(256) void ln_kernel(
    const float* __restrict__ X, const float* __restrict__ G,
    const float* __restrict__ Bt, u16* __restrict__ O)
{
  const int row = blockIdx.x;
  const int t = threadIdx.x;
  float4 xv = *(const float4*)&X[(size_t)row * D_MODEL + t * 4];
  float s  = xv.x + xv.y + xv.z + xv.w;
  float s2 = xv.x*xv.x + xv.y*xv.y + xv.z*xv.z + xv.w*xv.w;
  #pragma unroll
  for (int off = 32; off >= 1; off >>= 1){
    s  += __shfl_down(s,  off, 64);
    s2 += __shfl_down(s2, off, 64);
  }
  __shared__ float psum[4], psum2[4];
  const int wv = t >> 6, ln = t & 63;
  if (ln == 0){ psum[wv] = s; psum2[wv] = s2; }
  __syncthreads();
  float ts  = psum[0] + psum[1] + psum[2] + psum[3];
  float ts2 = psum2[0] + psum2[1] + psum2[2] + psum2[3];
  float mean = ts * (1.f / D_MODEL);
  float var  = ts2 * (1.f / D_MODEL) - mean * mean;
  float rstd = rsqrtf(var + 1e-6f);
  float4 g4 = *(const float4*)&G[t * 4];
  float4 b4 = *(const float4*)&Bt[t * 4];
  ushort4 o;
  o.x = f2b(g4.x * (xv.x - mean) * rstd + b4.x);
  o.y = f2b(g4.y * (xv.y - mean) * rstd + b4.y);
  o.z = f2b(g4.z * (xv.z - mean) * rstd + b4.z);
  o.w = f2b(g4.w * (xv.w - mean) * rstd + b4.w);
  *(ushort4*)&O[(size_t)row * D_MODEL + t * 4] = o;
}

// ---------------------------------------------------------------------------
// 3-stage pipelined GEMM core (AITER-style, prefetch distance 2):
// per iter: s_waitcnt vmcnt(6) [drains tile-k loads issued 2 iters ago;
// tile-k+1's 6 newest stay in flight] -> raw s_barrier (ds_reads already
// retired via MFMA operand waits) -> issue DMA(k+2) -> compute(k).
// Each load gets ~2 full iterations to land. BK=64 conflict-free swizzle.
// LDS = 3*(TM+TN)*64*2B.
// ---------------------------------------------------------------------------
template<int EPI, int OUTF, int TM, int TN>
__device__ __forceinline__ void gemm_core_p3(
    const u16* __restrict__ A, const u16* __restrict__ W,
    const float* __restrict__ bias, const float* resid,
    void* Cout, int K, int Ndim)
{
  constexpr int BK = 64;
  constexpr int MI = TM / 32;
  constexpr int NJ = TN / 32;
  constexpr int nAw = TM * BK / 2048;    // A DMA instrs per wave
  constexpr int nBw = TN * BK / 2048;
  __shared__ __align__(16) u16 sA[3][TM*BK];
  __shared__ __align__(16) u16 sB[3][TN*BK];
  const int t = threadIdx.x;
  const int w = t >> 6, lane = t & 63, lr = lane & 15, quad = lane >> 4;
  const int wm = (w & 1) * (TM/2), wn = (w >> 1) * (TN/2);
  const int m0 = blockIdx.x * TM, n0 = blockIdx.y * TN;
  const int sub = lane >> 3;             // CPR=8
  const int cl  = lane & 7;

  f32x4 acc[MI][NJ];
  #pragma unroll
  for (int i = 0; i < MI; i++)
    #pragma unroll
    for (int j = 0; j < NJ; j++) acc[i][j] = (f32x4){0.f,0.f,0.f,0.f};

  auto load_tile = [&](int k0, int buf){
    #pragma unroll
    for (int it = 0; it < nAw; it++){
      int R = (w*nAw + it) * 8;
      int gr = R + sub;
      int gc = (cl ^ (gr & 7)) * 8;
      gl_lds16(&A[(size_t)(m0 + gr) * K + k0 + gc], &sA[buf][R * BK]);
    }
    #pragma unroll
    for (int it = 0; it < nBw; it++){
      int R = (w*nBw + it) * 8;
      int gr = R + sub;
      int gc = (cl ^ (gr & 7)) * 8;
      gl_lds16(&W[(size_t)(n0 + gr) * K + k0 + gc], &sB[buf][R * BK]);
    }
  };

  load_tile(0, 0);
  load_tile(BK, 1);
  const int iters = K / BK;
  for (int it = 0; it < iters; it++){
    const int cur = it % 3;
    // drain tile-it loads (2 iters old); tile-it+1's 6 newest stay in flight
    asm volatile("s_waitcnt vmcnt(%0)" :: "i"(nAw + nBw) : "memory");
    asm volatile("s_barrier" ::: "memory");
    if (it + 2 < iters) load_tile((it + 2) * BK, (it + 2) % 3);
    #pragma unroll
    for (int ks = 0; ks < 2; ks++){
      short8 af[MI], bfr[NJ];
      #pragma unroll
      for (int i = 0; i < MI; i++)
        af[i]  = *(const short8*)&sA[cur][(wm + i*16 + lr)*BK + (((ks*4 + quad) ^ (lr & 7)) * 8)];
      #pragma unroll
      for (int j = 0; j < NJ; j++)
        bfr[j] = *(const short8*)&sB[cur][(wn + j*16 + lr)*BK + (((ks*4 + quad) ^ (lr & 7)) * 8)];
      #pragma unroll
      for (int i = 0; i < MI; i++)
        #pragma unroll
        for (int j = 0; j < NJ; j++)
          acc[i][j] = MFMA16(af[i], bfr[j], acc[i][j]);
    }
  }

  #pragma unroll
  for (int j = 0; j < NJ; j++){
    int gn = n0 + wn + j*16 + lr;
    float bb = bias[gn];
    #pragma unroll
    for (int i = 0; i < MI; i++){
      #pragma unroll
      for (int r = 0; r < 4; r++){
        int gm = m0 + wm + i*16 + quad*4 + r;   // C/D: row=quad*4+reg, col=lane&15
        size_t idx = (size_t)gm * Ndim + gn;
        float v = acc[i][j][r] + bb;
        if (EPI == 1){
          float p = v * (1.59576912f + 0.07135481f * v * v);
          float e = __builtin_amdgcn_exp2f(-1.44269504f * p);
          v = v * __builtin_amdgcn_rcpf(1.f + e);
        }
        if (EPI == 2) v += resid[idx];
        if (OUTF) ((float*)Cout)[idx] = v;
        else      ((u16*)Cout)[idx] = f2b(v);
      }
    }
  }
}

// ---------------------------------------------------------------------------
// Single-buffered core (proven) for Wo/FF1.
// ---------------------------------------------------------------------------
template<int EPI, int OUTF, int TM, int TN, int BK>
__device__ __forceinline__ void gemm_core(
    const u16* __restrict__ A, const u16* __restrict__ W,
    const float* __restrict__ bias, const float* resid,
    void* Cout, int K, int Ndim)
{
  constexpr int MI = TM / 32;
  constexpr int NJ = TN / 32;
  constexpr int CPR = BK / 8;
  constexpr int RPI = 512 / BK;
  constexpr int nAw = TM * BK / 512 / 4;
  constexpr int nBw = TN * BK / 512 / 4;
  __shared__ __align__(16) u16 sA[TM*BK];
  __shared__ __align__(16) u16 sB[TN*BK];
  const int t = threadIdx.x;
  const int w = t >> 6, lane = t & 63, lr = lane & 15, quad = lane >> 4;
  const int wm = (w & 1) * (TM/2), wn = (w >> 1) * (TN/2);
  const int m0 = blockIdx.x * TM, n0 = blockIdx.y * TN;
  const int sub = lane / CPR;
  const int cl  = lane % CPR;

  f32x4 acc[MI][NJ];
  #pragma unroll
  for (int i = 0; i < MI; i++)
    #pragma unroll
    for (int j = 0; j < NJ; j++) acc[i][j] = (f32x4){0.f,0.f,0.f,0.f};

  for (int k0 = 0; k0 < K; k0 += BK){
    __syncthreads();
    #pragma unroll
    for (int it = 0; it < nAw; it++){
      int R = (w*nAw + it) * RPI;
      int gr = R + sub;
      int gc = (cl ^ (gr & 7)) * 8;
      gl_lds16(&A[(size_t)(m0 + gr) * K + k0 + gc], &sA[R * BK]);
    }
    #pragma unroll
    for (int it = 0; it < nBw; it++){
      int R = (w*nBw + it) * RPI;
      int gr = R + sub;
      int gc = (cl ^ (gr & 7)) * 8;
      gl_lds16(&W[(size_t)(n0 + gr) * K + k0 + gc], &sB[R * BK]);
    }
    __syncthreads();
    #pragma unroll
    for (int ks = 0; ks < BK/32; ks++){
      short8 af[MI], bfr[NJ];
      #pragma unroll
      for (int i = 0; i < MI; i++)
        af[i]  = *(const short8*)&sA[(wm + i*16 + lr)*BK + (((ks*4 + quad) ^ (lr & 7)) * 8)];
      #pragma unroll
      for (int j = 0; j < NJ; j++)
        bfr[j] = *(const short8*)&sB[(wn + j*16 + lr)*BK + (((ks*4 + quad) ^ (lr & 7)) * 8)];
      #pragma unroll
      for (int i = 0; i < MI; i++)
        #pragma unroll
        for (int j = 0; j < NJ; j++)
          acc[i][j] = MFMA16(af[i], bfr[j], acc[i][j]);
    }
  }

  #pragma unroll
  for (int j = 0; j < NJ; j++){
    int gn = n0 + wn + j*16 + lr;
    float bb = bias[gn];
    #pragma unroll
    for (int i = 0; i < MI; i++){
      #pragma unroll
      for (int r = 0; r < 4; r++){
        int gm = m0 + wm + i*16 + quad*4 + r;
        size_t idx = (size_t)gm * Ndim + gn;
        float v = acc[i][j][r] + bb;
        if (EPI == 1){
          float p = v * (1.59576912f + 0.07135481f * v * v);
          float e = __builtin_amdgcn_exp2f(-1.44269504f * p);
          v = v * __builtin_amdgcn_rcpf(1.f + e);
        }
        if (EPI == 2) v += resid[idx];
        if (OUTF) ((float*)Cout)[idx] = v;
        else      ((u16*)Cout)[idx] = f2b(v);
      }
    }
  }
}

__global__ __launch_bounds__(256,2) void gemm_wo(
    const u16* __restrict__ A, const u16* __restrict__ W,
    const float* __restrict__ bias, const float* resid, void* Cout)
{ gemm_core<2,1,64,128,128>(A, W, bias, resid, Cout, D_MODEL, D_MODEL); }

__global__ __launch_bounds__(256,2) void gemm_ff1(
    const u16* __restrict__ A, const u16* __restrict__ W,
    const float* __restrict__ bias, void* Cout)
{ gemm_core<1,0,128,128,64>(A, W, bias, nullptr, Cout, D_MODEL, D_FF); }

__global__ __launch_bounds__(256,2) void gemm_ff2(
    const u16* __restrict__ A, const u16* __restrict__ W,
    const float* __restrict__ bias, const float* resid, void* Cout)
{ gemm_core_p3<2,1,64,128>(A, W, bias, resid, Cout, D_FF, D_MODEL); }

// ---------------------------------------------------------------------------
// QKV GEMM: 128x128 tile, wave 64x64, BK=64, grid (32, 8, 3). z selects
// {Q,K,V}. Q pre-scaled by 0.125*log2(e). V (z==2) written TRANSPOSED to vt.
// ---------------------------------------------------------------------------
__global__ __launch_bounds__(256,2) void gemm_qkv(
    const u16* __restrict__ A,
    const u16* __restrict__ Wq, const float* __restrict__ bq,
    const u16* __restrict__ Wk, const float* __restrict__ bk,
    const u16* __restrict__ Wv, const float* __restrict__ bv,
    u16* __restrict__ Qo, u16* __restrict__ Ko, u16* __restrict__ Vo)
{
  __shared__ __align__(16) u16 smem[2*128*64];   // sA | sB; reused for V-transpose
  u16* sA = smem;
  u16* sB = smem + 128*64;
  const u16* W; const float* bias; float scale;
  if (blockIdx.z == 0){ W = Wq; bias = bq; scale = 0.125f * 1.44269504f; }
  else if (blockIdx.z == 1){ W = Wk; bias = bk; scale = 1.f; }
  else { W = Wv; bias = bv; scale = 1.f; }

  const int t = threadIdx.x;
  const int w = t >> 6, lane = t & 63, lr = lane & 15, quad = lane >> 4;
  const int wm = (w & 1) * 64, wn = (w >> 1) * 64;
  const int m0 = blockIdx.x * 128, n0 = blockIdx.y * 128;
  const int srow = lane >> 3;
  const int scol = ((lane & 7) ^ srow) * 8;
  const int K = D_MODEL;

  f32x4 acc[4][4];
  #pragma unroll
  for (int i = 0; i < 4; i++)
    #pragma unroll
    for (int j = 0; j < 4; j++) acc[i][j] = (f32x4){0.f,0.f,0.f,0.f};

  for (int k0 = 0; k0 < K; k0 += 64){
    __syncthreads();
    #pragma unroll
    for (int it = 0; it < 4; it++){
      gl_lds16(&A[(size_t)(m0 + it*32 + w*8 + srow) * K + k0 + scol], &sA[(it*32 + w*8) * 64]);
      gl_lds16(&W[(size_t)(n0 + it*32 + w*8 + srow) * K + k0 + scol], &sB[(it*32 + w*8) * 64]);
    }
    __syncthreads();
    #pragma unroll
    for (int ks = 0; ks < 2; ks++){
      short8 af[4], bfr[4];
      #pragma unroll
      for (int i = 0; i < 4; i++)
        af[i]  = *(const short8*)&sA[(wm + i*16 + lr)*64 + (((ks*4 + quad) ^ (lr & 7)) * 8)];
      #pragma unroll
      for (int j = 0; j < 4; j++)
        bfr[j] = *(const short8*)&sB[(wn + j*16 + lr)*64 + (((ks*4 + quad) ^ (lr & 7)) * 8)];
      #pragma unroll
      for (int i = 0; i < 4; i++)
        #pragma unroll
        for (int j = 0; j < 4; j++)
          acc[i][j] = MFMA16(af[i], bfr[j], acc[i][j]);
    }
  }

  if (blockIdx.z == 2){
    // --- V: transpose in LDS, write vt[BH][dk][SEQ] with b128 stores ---
    __syncthreads();   // all waves done reading sA/sB
    #pragma unroll
    for (int j = 0; j < 4; j++){
      int dl = wn + j*16 + lr;            // local dim 0..127
      float bb = bias[n0 + dl];
      #pragma unroll
      for (int i = 0; i < 4; i++){
        #pragma unroll
        for (int r = 0; r < 4; r++){
          int tok = wm + i*16 + quad*4 + r;   // local token 0..127
          int phys = (((tok >> 3) ^ (dl & 7)) * 8) + (tok & 7);
          smem[dl*128 + phys] = f2b(acc[i][j][r] + bb);
        }
      }
    }
    __syncthreads();
    const int b = m0 >> 11, sq0 = m0 & 2047, hh0 = n0 >> 6;
    #pragma unroll
    for (int it = 0; it < 8; it++){
      int idx = it*256 + t;
      int drow = idx >> 4, c = idx & 15;
      float4 val = *(const float4*)&smem[drow*128 + ((c ^ (drow & 7)) * 8)];
      int hh = hh0 + (drow >> 6), d = drow & 63;
      *(float4*)&Vo[(((size_t)(b*N_HEADS + hh))*DKH + d)*SEQ + sq0 + c*8] = val;
    }
    return;
  }

  u16* out = (blockIdx.z == 0) ? Qo : Ko;
  #pragma unroll
  for (int j = 0; j < 4; j++){
    int gn = n0 + wn + j*16 + lr;
    int hh = gn >> 6, d = gn & 63;
    float bb = bias[gn];
    #pragma unroll
    for (int i = 0; i < 4; i++){
      #pragma unroll
      for (int r = 0; r < 4; r++){
        int gm = m0 + wm + i*16 + quad*4 + r;
        int b = gm >> 11, sq = gm & 2047;
        float v = (acc[i][j][r] + bb) * scale;
        out[(((size_t)(b * N_HEADS + hh)) * SEQ + sq) * DKH + d] = f2b(v);
      }
    }
  }
}

// ---------------------------------------------------------------------------
// Flash attention (round-7 proven): 512 threads = 8 waves x 16 q-rows.
// bh on blockIdx.x. gl_lds16 swizzled staging; swizzled sP. LDS 64 KB.
// ---------------------------------------------------------------------------
__global__ __launch_bounds__(512,2) void attn_kernel(
    const u16* __restrict__ Q, const u16* __restrict__ K,
    const u16* __restrict__ Vt, u16* __restrict__ ctx)
{
  __shared__ __align__(16) u16 sK[128*64];
  __shared__ __align__(16) u16 sVt[64*128];
  __shared__ __align__(16) u16 sP[8*16*128];   // per-wave 16 q x 128 kv

  const int t = threadIdx.x, w = t >> 6, lane = t & 63;
  const int lr = lane & 15, quad = lane >> 4;
  const int bh = blockIdx.x;
  const int q0 = blockIdx.y * 128;
  const u16* Qp = Q + ((size_t)bh * SEQ + q0) * DKH;
  const u16* Kp = K + (size_t)bh * SEQ * DKH;
  const u16* Vp = Vt + (size_t)bh * DKH * SEQ;

  short8 qf[2];
  #pragma unroll
  for (int ks = 0; ks < 2; ks++)
    qf[ks] = *(const short8*)&Qp[(size_t)(w*16 + lr) * DKH + ks*32 + quad*8];

  short8 ones;
  #pragma unroll
  for (int e = 0; e < 8; e++) ones[e] = (short)0x3F80;

  f32x4 acco[4];   // ctx: q=quad*4+r, d=jc*16+lr
  f32x4 accl;      // l:   q=quad*4+r
  accl = (f32x4){0.f,0.f,0.f,0.f};
  #pragma unroll
  for (int jc = 0; jc < 4; jc++) acco[jc] = (f32x4){0.f,0.f,0.f,0.f};

  const int srow = lane >> 3;
  const int sc8  = ((lane & 7) ^ srow) * 8;
  const int lro  = lane >> 4, cl = lane & 15;

  for (int kt = 0; kt < SEQ/128; kt++){
    const int s0 = kt * 128;
    __syncthreads();
    #pragma unroll
    for (int it = 0; it < 2; it++)     // K tile 128 x 64
      gl_lds16(&Kp[(size_t)(s0 + it*64 + w*8 + srow) * DKH + sc8],
               &sK[(it*64 + w*8) * 64]);
    #pragma unroll
    for (int it = 0; it < 2; it++){    // Vt tile 64 x 128
      int R = w*8 + it*4;
      int gr = R + lro;
      int gc = (cl ^ (gr & 7)) * 8;
      gl_lds16(&Vp[(size_t)gr * SEQ + s0 + gc], &sVt[R * 128]);
    }
    __syncthreads();

    // S^T: A=K rows (kv), B=Q rows (q). D[kv=j*16+quad*4+r][q=lr]
    f32x4 st_[8];
    #pragma unroll
    for (int j = 0; j < 8; j++) st_[j] = (f32x4){0.f,0.f,0.f,0.f};
    #pragma unroll
    for (int ks = 0; ks < 2; ks++){
      #pragma unroll
      for (int j = 0; j < 8; j++){
        short8 kf = *(const short8*)&sK[(j*16 + lr)*64 + (((ks*4 + quad) ^ (lr & 7)) * 8)];
        st_[j] = MFMA16(kf, qf[ks], st_[j]);
      }
    }

    // P = 2^(S^T), pack pairs, b64 to swizzled sP[q=lr][kv]
    #pragma unroll
    for (int j = 0; j < 8; j++){
      float p0 = __builtin_amdgcn_exp2f(st_[j][0]);
      float p1 = __builtin_amdgcn_exp2f(st_[j][1]);
      float p2 = __builtin_amdgcn_exp2f(st_[j][2]);
      float p3 = __builtin_amdgcn_exp2f(st_[j][3]);
      uint2 pv; pv.x = pk_bf16(p0, p1); pv.y = pk_bf16(p2, p3);
      int c = j*2 + (quad >> 1);
      *(uint2*)&sP[w*2048 + lr*128 + ((c ^ (lr & 7)) * 8) + (quad & 1)*4] = pv;
    }

    // PV + l: A=P rows (q), B=Vt rows (d) / ones
    #pragma unroll
    for (int ks = 0; ks < 4; ks++){
      short8 pf = *(const short8*)&sP[w*2048 + lr*128 + (((ks*4 + quad) ^ (lr & 7)) * 8)];
      accl = MFMA16(pf, ones, accl);
      #pragma unroll
      for (int jc = 0; jc < 4; jc++){
        short8 vf = *(const short8*)&sVt[(jc*16 + lr)*128 + (((ks*4 + quad) ^ (lr & 7)) * 8)];
        acco[jc] = MFMA16(pf, vf, acco[jc]);
      }
    }
  }

  // epilogue: normalize by l, scatter to [B,S,H*dk]
  const int bq = bh >> 4, hh = bh & 15;
  u16* op = ctx + ((size_t)bq * SEQ + q0) * D_MODEL + hh * DKH;
  #pragma unroll
  for (int r = 0; r < 4; r++){
    float rl = 1.f / accl[r];
    int row = w*16 + quad*4 + r;
    #pragma unroll
    for (int jc = 0; jc < 4; jc++)
      op[(size_t)row * D_MODEL + jc*16 + lr] = f2b(acco[jc][r] * rl);
  }
}

// ---------------------------------------------------------------------------
extern "C" void kernel_launch(void* const* d_in, const int* in_sizes, int n_in,
                              void* d_out, int out_size, void* d_ws, size_t ws_size,
                              hipStream_t stream)
{
  const float* x   = (const float*)d_in[0];
  const float* Wq  = (const float*)d_in[1];
  const float* bq  = (const float*)d_in[2];
  const float* Wk  = (const float*)d_in[3];
  const float* bk  = (const float*)d_in[4];
  const float* Wv  = (const float*)d_in[5];
  const float* bv  = (const float*)d_in[6];
  const float* Wo  = (const float*)d_in[7];
  const float* bo  = (const float*)d_in[8];
  const float* W1  = (const float*)d_in[9];
  const float* b1  = (const float*)d_in[10];
  const float* W2  = (const float*)d_in[11];
  const float* b2  = (const float*)d_in[12];
  const float* g1  = (const float*)d_in[13];
  const float* be1 = (const float*)d_in[14];
  const float* g2  = (const float*)d_in[15];
  const float* be2 = (const float*)d_in[16];

  char* ws = (char*)d_ws;
  const size_t MB = 1024ull * 1024ull;
  u16* wqb = (u16*)(ws + 0*MB);
  u16* wkb = (u16*)(ws + 2*MB);
  u16* wvb = (u16*)(ws + 4*MB);
  u16* wob = (u16*)(ws + 6*MB);
  u16* w1b = (u16*)(ws + 8*MB);    // 8 MB (4096x1024)
  u16* w2b = (u16*)(ws + 16*MB);   // 8 MB (1024x4096)
  u16* h   = (u16*)(ws + 24*MB);   // bf16 activations; reused as h2
  u16* q   = (u16*)(ws + 32*MB);   // [B,H,S,dk]
  u16* k   = (u16*)(ws + 40*MB);
  u16* ctx = (u16*)(ws + 48*MB);   // attn output
  u16* vt  = (u16*)(ws + 56*MB);   // [B,H,dk,S] — written by gemm_qkv z==2
  u16* ff  = (u16*)(ws + 32*MB);   // 32 MB [M,D_FF]; q/k/ctx/vt dead by then
  u16* h2  = h;
  float* x1 = (float*)d_out;       // attn residual output (fp32) in d_out

  // 0. weights -> bf16 + LN1 fused (7th y-slice)
  cvt_ln_kernel<<<dim3(4096, 7), 256, 0, stream>>>(
      Wq, Wk, Wv, Wo, W1, W2, wqb, wkb, wvb, wob, w1b, w2b,
      x, g1, be1, h);

  // 1. QKV projections (128x128, wave 64x64); V written transposed to vt
  gemm_qkv<<<dim3(M_TOK/128, D_MODEL/128, 3), 256, 0, stream>>>(
      h, wqb, bq, wkb, bk, wvb, bv, q, k, vt);
  // 2. flash attention (512 threads, 8 waves)
  attn_kernel<<<dim3(BATCH*N_HEADS, SEQ/128), 512, 0, stream>>>(q, k, vt, ctx);
  // 3. Wo + residual(x) -> x1 fp32; single-buf 64x128 BK=128 (proven)
  gemm_wo<<<dim3(M_TOK/64, D_MODEL/128), 256, 0, stream>>>(
      ctx, wob, bo, x, (void*)x1);
  // 4. LN2 (fp32 x1 -> bf16 h2)
  ln_kernel<<<M_TOK, 256, 0, stream>>>(x1, g2, be2, h2);
  // 5. FF1 + GELU -> bf16 ff; 128x128 BK=64 single-buf
  gemm_ff1<<<dim3(M_TOK/128, D_FF/128), 256, 0, stream>>>(
      h2, w1b, b1, (void*)ff);
  // 6. FF2 + residual(x1) -> d_out fp32; 3-stage pipeline, 64x128 BK=64
  gemm_ff2<<<dim3(M_TOK/64, D_MODEL/128), 256, 0, stream>>>(
      ff, w2b, b2, x1, d_out);
}

// Round 13
// 316.803 us; speedup vs baseline: 1.0431x; 1.0170x over previous
//
#include <hip/hip_runtime.h>
#include <stdint.h>

#define D_MODEL 1024
#define N_HEADS 16
#define DKH     64
#define D_FF    4096
#define BATCH   2
#define SEQ     2048
#define M_TOK   (BATCH*SEQ)   // 4096 tokens

typedef unsigned short u16;
typedef __attribute__((ext_vector_type(8))) short short8;   // 8 x bf16 = 4 VGPRs
typedef __attribute__((ext_vector_type(4))) float f32x4;

__device__ __forceinline__ u16 f2b(float f){
  union { float f; uint32_t i; } c; c.f = f;
  uint32_t x = c.i;
  uint32_t r = x + 0x7fffu + ((x >> 16) & 1u);   // RNE
  return (u16)(r >> 16);
}

// packed 2xfp32 -> 2xbf16 (RNE), single VALU op on gfx950
__device__ __forceinline__ uint32_t pk_bf16(float a, float b){
  uint32_t d;
  asm("v_cvt_pk_bf16_f32 %0, %1, %2" : "=v"(d) : "v"(a), "v"(b));
  return d;
}

// async global->LDS, 16B per lane; dest = wave-uniform base + lane*16
__device__ __forceinline__ void gl_lds16(const u16* g, u16* l){
  __builtin_amdgcn_global_load_lds(
      (const __attribute__((address_space(1))) void*)g,
      (__attribute__((address_space(3))) void*)l, 16, 0, 0);
}

#define MFMA16(a,b,c) __builtin_amdgcn_mfma_f32_16x16x32_bf16((a),(b),(c),0,0,0)

// ---------------------------------------------------------------------------
// Fused weight-cvt (6 matrices) + LN1 (y==6 slice).
// ---------------------------------------------------------------------------
__global__ __launch_bounds__(256) void cvt_ln_kernel(
    const float* __restrict__ s0, const float* __restrict__ s1,
    const float* __restrict__ s2, const float* __restrict__ s3,
    const float* __restrict__ s4, const float* __restrict__ s5,
    u16* __restrict__ d0, u16* __restrict__ d1, u16* __restrict__ d2,
    u16* __restrict__ d3, u16* __restrict__ d4, u16* __restrict__ d5,
    const float* __restrict__ X, const float* __restrict__ G,
    const float* __restrict__ Bt, u16* __restrict__ O)
{
  __shared__ float psum[4], psum2[4];
  if (blockIdx.y == 6){
    const int row = blockIdx.x;
    const int t = threadIdx.x;
    float4 xv = *(const float4*)&X[(size_t)row * D_MODEL + t * 4];
    float s  = xv.x + xv.y + xv.z + xv.w;
    float s2 = xv.x*xv.x + xv.y*xv.y + xv.z*xv.z + xv.w*xv.w;
    #pragma unroll
    for (int off = 32; off >= 1; off >>= 1){
      s  += __shfl_down(s,  off, 64);
      s2 += __shfl_down(s2, off, 64);
    }
    const int wv = t >> 6, ln = t & 63;
    if (ln == 0){ psum[wv] = s; psum2[wv] = s2; }
    __syncthreads();
    float ts  = psum[0] + psum[1] + psum[2] + psum[3];
    float ts2 = psum2[0] + psum2[1] + psum2[2] + psum2[3];
    float mean = ts * (1.f / D_MODEL);
    float var  = ts2 * (1.f / D_MODEL) - mean * mean;
    float rstd = rsqrtf(var + 1e-6f);
    float4 g4 = *(const float4*)&G[t * 4];
    float4 b4 = *(const float4*)&Bt[t * 4];
    ushort4 o;
    o.x = f2b(g4.x * (xv.x - mean) * rstd + b4.x);
    o.y = f2b(g4.y * (xv.y - mean) * rstd + b4.y);
    o.z = f2b(g4.z * (xv.z - mean) * rstd + b4.z);
    o.w = f2b(g4.w * (xv.w - mean) * rstd + b4.w);
    *(ushort4*)&O[(size_t)row * D_MODEL + t * 4] = o;
    return;
  }
  const float* s; u16* d; int n;
  switch (blockIdx.y){
    case 0: s=s0; d=d0; n=D_MODEL*D_MODEL; break;
    case 1: s=s1; d=d1; n=D_MODEL*D_MODEL; break;
    case 2: s=s2; d=d2; n=D_MODEL*D_MODEL; break;
    case 3: s=s3; d=d3; n=D_MODEL*D_MODEL; break;
    case 4: s=s4; d=d4; n=D_FF*D_MODEL;   break;
    default: s=s5; d=d5; n=D_MODEL*D_FF;  break;
  }
  int i = (blockIdx.x * 256 + threadIdx.x) * 4;
  if (i < n){
    float4 f = *(const float4*)&s[i];
    ushort4 o; o.x = f2b(f.x); o.y = f2b(f.y); o.z = f2b(f.z); o.w = f2b(f.w);
    *(ushort4*)&d[i] = o;
  }
}

// ---------------------------------------------------------------------------
// LayerNorm (standalone, for LN2): fp32 in, bf16 out.
// ---------------------------------------------------------------------------
__global__ __launch_bounds__(256) void ln_kernel(
    const float* __restrict__ X, const float* __restrict__ G,
    const float* __restrict__ Bt, u16* __restrict__ O)
{
  const int row = blockIdx.x;
  const int t = threadIdx.x;
  float4 xv = *(const float4*)&X[(size_t)row * D_MODEL + t * 4];
  float s  = xv.x + xv.y + xv.z + xv.w;
  float s2 = xv.x*xv.x + xv.y*xv.y + xv.z*xv.z + xv.w*xv.w;
  #pragma unroll
  for (int off = 32; off >= 1; off >>= 1){
    s  += __shfl_down(s,  off, 64);
    s2 += __shfl_down(s2, off, 64);
  }
  __shared__ float psum[4], psum2[4];
  const int wv = t >> 6, ln = t & 63;
  if (ln == 0){ psum[wv] = s; psum2[wv] = s2; }
  __syncthreads();
  float ts  = psum[0] + psum[1] + psum[2] + psum[3];
  float ts2 = psum2[0] + psum2[1] + psum2[2] + psum2[3];
  float mean = ts * (1.f / D_MODEL);
  float var  = ts2 * (1.f / D_MODEL) - mean * mean;
  float rstd = rsqrtf(var + 1e-6f);
  float4 g4 = *(const float4*)&G[t * 4];
  float4 b4 = *(const float4*)&Bt[t * 4];
  ushort4 o;
  o.x = f2b(g4.x * (xv.x - mean) * rstd + b4.x);
  o.y = f2b(g4.y * (xv.y - mean) * rstd + b4.y);
  o.z = f2b(g4.z * (xv.z - mean) * rstd + b4.z);
  o.w = f2b(g4.w * (xv.w - mean) * rstd + b4.w);
  *(ushort4*)&O[(size_t)row * D_MODEL + t * 4] = o;
}

// ---------------------------------------------------------------------------
// Single-buffered GEMM core (proven best): TM x TN x BK, 4 waves 2x2.
// m on blockIdx.x (XCD affinity). XOR-swizzled LDS + global_load_lds staging.
// Pipelining at depth 0/1/2 measured identical or worse (r10-r12): the
// per-iteration cost is issue/barrier machinery, not load latency — fewer
// iterations (BK=128) is the only lever that moved FF2 (65->54).
// EPI: 0=none, 1=GELU, 2=+resid. OUTF=1 -> fp32 out else bf16.
// ---------------------------------------------------------------------------
template<int EPI, int OUTF, int TM, int TN, int BK>
__device__ __forceinline__ void gemm_core(
    const u16* __restrict__ A, const u16* __restrict__ W,
    const float* __restrict__ bias, const float* resid,
    void* Cout, int K, int Ndim)
{
  constexpr int MI = TM / 32;
  constexpr int NJ = TN / 32;
  constexpr int CPR = BK / 8;
  constexpr int RPI = 512 / BK;
  constexpr int nAw = TM * BK / 512 / 4;
  constexpr int nBw = TN * BK / 512 / 4;
  __shared__ __align__(16) u16 sA[TM*BK];
  __shared__ __align__(16) u16 sB[TN*BK];
  const int t = threadIdx.x;
  const int w = t >> 6, lane = t & 63, lr = lane & 15, quad = lane >> 4;
  const int wm = (w & 1) * (TM/2), wn = (w >> 1) * (TN/2);
  const int m0 = blockIdx.x * TM, n0 = blockIdx.y * TN;
  const int sub = lane / CPR;
  const int cl  = lane % CPR;

  f32x4 acc[MI][NJ];
  #pragma unroll
  for (int i = 0; i < MI; i++)
    #pragma unroll
    for (int j = 0; j < NJ; j++) acc[i][j] = (f32x4){0.f,0.f,0.f,0.f};

  for (int k0 = 0; k0 < K; k0 += BK){
    __syncthreads();
    #pragma unroll
    for (int it = 0; it < nAw; it++){
      int R = (w*nAw + it) * RPI;
      int gr = R + sub;
      int gc = (cl ^ (gr & 7)) * 8;
      gl_lds16(&A[(size_t)(m0 + gr) * K + k0 + gc], &sA[R * BK]);
    }
    #pragma unroll
    for (int it = 0; it < nBw; it++){
      int R = (w*nBw + it) * RPI;
      int gr = R + sub;
      int gc = (cl ^ (gr & 7)) * 8;
      gl_lds16(&W[(size_t)(n0 + gr) * K + k0 + gc], &sB[R * BK]);
    }
    __syncthreads();
    #pragma unroll
    for (int ks = 0; ks < BK/32; ks++){
      short8 af[MI], bfr[NJ];
      #pragma unroll
      for (int i = 0; i < MI; i++)
        af[i]  = *(const short8*)&sA[(wm + i*16 + lr)*BK + (((ks*4 + quad) ^ (lr & 7)) * 8)];
      #pragma unroll
      for (int j = 0; j < NJ; j++)
        bfr[j] = *(const short8*)&sB[(wn + j*16 + lr)*BK + (((ks*4 + quad) ^ (lr & 7)) * 8)];
      #pragma unroll
      for (int i = 0; i < MI; i++)
        #pragma unroll
        for (int j = 0; j < NJ; j++)
          acc[i][j] = MFMA16(af[i], bfr[j], acc[i][j]);
    }
  }

  #pragma unroll
  for (int j = 0; j < NJ; j++){
    int gn = n0 + wn + j*16 + lr;
    float bb = bias[gn];
    #pragma unroll
    for (int i = 0; i < MI; i++){
      #pragma unroll
      for (int r = 0; r < 4; r++){
        int gm = m0 + wm + i*16 + quad*4 + r;   // C/D: row=quad*4+reg, col=lane&15
        size_t idx = (size_t)gm * Ndim + gn;
        float v = acc[i][j][r] + bb;
        if (EPI == 1){
          float p = v * (1.59576912f + 0.07135481f * v * v);
          float e = __builtin_amdgcn_exp2f(-1.44269504f * p);
          v = v * __builtin_amdgcn_rcpf(1.f + e);
        }
        if (EPI == 2) v += resid[idx];
        if (OUTF) ((float*)Cout)[idx] = v;
        else      ((u16*)Cout)[idx] = f2b(v);
      }
    }
  }
}

__global__ __launch_bounds__(256,2) void gemm_wo(
    const u16* __restrict__ A, const u16* __restrict__ W,
    const float* __restrict__ bias, const float* resid, void* Cout)
{ gemm_core<2,1,64,128,128>(A, W, bias, resid, Cout, D_MODEL, D_MODEL); }

__global__ __launch_bounds__(256,2) void gemm_ff1(
    const u16* __restrict__ A, const u16* __restrict__ W,
    const float* __restrict__ bias, void* Cout)
{ gemm_core<1,0,128,128,64>(A, W, bias, nullptr, Cout, D_MODEL, D_FF); }

__global__ __launch_bounds__(256,2) void gemm_ff2(
    const u16* __restrict__ A, const u16* __restrict__ W,
    const float* __restrict__ bias, const float* resid, void* Cout)
{ gemm_core<2,1,64,128,128>(A, W, bias, resid, Cout, D_FF, D_MODEL); }

// ---------------------------------------------------------------------------
// QKV GEMM: 128x128 tile, wave 64x64, BK=64, grid (32, 8, 3). z selects
// {Q,K,V}. Q pre-scaled by 0.125*log2(e). V (z==2) written TRANSPOSED to vt.
// ---------------------------------------------------------------------------
__global__ __launch_bounds__(256,2) void gemm_qkv(
    const u16* __restrict__ A,
    const u16* __restrict__ Wq, const float* __restrict__ bq,
    const u16* __restrict__ Wk, const float* __restrict__ bk,
    const u16* __restrict__ Wv, const float* __restrict__ bv,
    u16* __restrict__ Qo, u16* __restrict__ Ko, u16* __restrict__ Vo)
{
  __shared__ __align__(16) u16 smem[2*128*64];   // sA | sB; reused for V-transpose
  u16* sA = smem;
  u16* sB = smem + 128*64;
  const u16* W; const float* bias; float scale;
  if (blockIdx.z == 0){ W = Wq; bias = bq; scale = 0.125f * 1.44269504f; }
  else if (blockIdx.z == 1){ W = Wk; bias = bk; scale = 1.f; }
  else { W = Wv; bias = bv; scale = 1.f; }

  const int t = threadIdx.x;
  const int w = t >> 6, lane = t & 63, lr = lane & 15, quad = lane >> 4;
  const int wm = (w & 1) * 64, wn = (w >> 1) * 64;
  const int m0 = blockIdx.x * 128, n0 = blockIdx.y * 128;
  const int srow = lane >> 3;
  const int scol = ((lane & 7) ^ srow) * 8;
  const int K = D_MODEL;

  f32x4 acc[4][4];
  #pragma unroll
  for (int i = 0; i < 4; i++)
    #pragma unroll
    for (int j = 0; j < 4; j++) acc[i][j] = (f32x4){0.f,0.f,0.f,0.f};

  for (int k0 = 0; k0 < K; k0 += 64){
    __syncthreads();
    #pragma unroll
    for (int it = 0; it < 4; it++){
      gl_lds16(&A[(size_t)(m0 + it*32 + w*8 + srow) * K + k0 + scol], &sA[(it*32 + w*8) * 64]);
      gl_lds16(&W[(size_t)(n0 + it*32 + w*8 + srow) * K + k0 + scol], &sB[(it*32 + w*8) * 64]);
    }
    __syncthreads();
    #pragma unroll
    for (int ks = 0; ks < 2; ks++){
      short8 af[4], bfr[4];
      #pragma unroll
      for (int i = 0; i < 4; i++)
        af[i]  = *(const short8*)&sA[(wm + i*16 + lr)*64 + (((ks*4 + quad) ^ (lr & 7)) * 8)];
      #pragma unroll
      for (int j = 0; j < 4; j++)
        bfr[j] = *(const short8*)&sB[(wn + j*16 + lr)*64 + (((ks*4 + quad) ^ (lr & 7)) * 8)];
      #pragma unroll
      for (int i = 0; i < 4; i++)
        #pragma unroll
        for (int j = 0; j < 4; j++)
          acc[i][j] = MFMA16(af[i], bfr[j], acc[i][j]);
    }
  }

  if (blockIdx.z == 2){
    // --- V: transpose in LDS, write vt[BH][dk][SEQ] with b128 stores ---
    __syncthreads();   // all waves done reading sA/sB
    #pragma unroll
    for (int j = 0; j < 4; j++){
      int dl = wn + j*16 + lr;            // local dim 0..127
      float bb = bias[n0 + dl];
      #pragma unroll
      for (int i = 0; i < 4; i++){
        #pragma unroll
        for (int r = 0; r < 4; r++){
          int tok = wm + i*16 + quad*4 + r;   // local token 0..127
          int phys = (((tok >> 3) ^ (dl & 7)) * 8) + (tok & 7);
          smem[dl*128 + phys] = f2b(acc[i][j][r] + bb);
        }
      }
    }
    __syncthreads();
    const int b = m0 >> 11, sq0 = m0 & 2047, hh0 = n0 >> 6;
    #pragma unroll
    for (int it = 0; it < 8; it++){
      int idx = it*256 + t;
      int drow = idx >> 4, c = idx & 15;
      float4 val = *(const float4*)&smem[drow*128 + ((c ^ (drow & 7)) * 8)];
      int hh = hh0 + (drow >> 6), d = drow & 63;
      *(float4*)&Vo[(((size_t)(b*N_HEADS + hh))*DKH + d)*SEQ + sq0 + c*8] = val;
    }
    return;
  }

  u16* out = (blockIdx.z == 0) ? Qo : Ko;
  #pragma unroll
  for (int j = 0; j < 4; j++){
    int gn = n0 + wn + j*16 + lr;
    int hh = gn >> 6, d = gn & 63;
    float bb = bias[gn];
    #pragma unroll
    for (int i = 0; i < 4; i++){
      #pragma unroll
      for (int r = 0; r < 4; r++){
        int gm = m0 + wm + i*16 + quad*4 + r;
        int b = gm >> 11, sq = gm & 2047;
        float v = (acc[i][j][r] + bb) * scale;
        out[(((size_t)(b * N_HEADS + hh)) * SEQ + sq) * DKH + d] = f2b(v);
      }
    }
  }
}

// ---------------------------------------------------------------------------
// Flash attention (round-7 proven): 512 threads = 8 waves x 16 q-rows.
// bh on blockIdx.x. gl_lds16 swizzled staging; swizzled sP. LDS 64 KB.
// ---------------------------------------------------------------------------
__global__ __launch_bounds__(512,2) void attn_kernel(
    const u16* __restrict__ Q, const u16* __restrict__ K,
    const u16* __restrict__ Vt, u16* __restrict__ ctx)
{
  __shared__ __align__(16) u16 sK[128*64];
  __shared__ __align__(16) u16 sVt[64*128];
  __shared__ __align__(16) u16 sP[8*16*128];   // per-wave 16 q x 128 kv

  const int t = threadIdx.x, w = t >> 6, lane = t & 63;
  const int lr = lane & 15, quad = lane >> 4;
  const int bh = blockIdx.x;
  const int q0 = blockIdx.y * 128;
  const u16* Qp = Q + ((size_t)bh * SEQ + q0) * DKH;
  const u16* Kp = K + (size_t)bh * SEQ * DKH;
  const u16* Vp = Vt + (size_t)bh * DKH * SEQ;

  short8 qf[2];
  #pragma unroll
  for (int ks = 0; ks < 2; ks++)
    qf[ks] = *(const short8*)&Qp[(size_t)(w*16 + lr) * DKH + ks*32 + quad*8];

  short8 ones;
  #pragma unroll
  for (int e = 0; e < 8; e++) ones[e] = (short)0x3F80;

  f32x4 acco[4];   // ctx: q=quad*4+r, d=jc*16+lr
  f32x4 accl;      // l:   q=quad*4+r
  accl = (f32x4){0.f,0.f,0.f,0.f};
  #pragma unroll
  for (int jc = 0; jc < 4; jc++) acco[jc] = (f32x4){0.f,0.f,0.f,0.f};

  const int srow = lane >> 3;
  const int sc8  = ((lane & 7) ^ srow) * 8;
  const int lro  = lane >> 4, cl = lane & 15;

  for (int kt = 0; kt < SEQ/128; kt++){
    const int s0 = kt * 128;
    __syncthreads();
    #pragma unroll
    for (int it = 0; it < 2; it++)     // K tile 128 x 64
      gl_lds16(&Kp[(size_t)(s0 + it*64 + w*8 + srow) * DKH + sc8],
               &sK[(it*64 + w*8) * 64]);
    #pragma unroll
    for (int it = 0; it < 2; it++){    // Vt tile 64 x 128
      int R = w*8 + it*4;
      int gr = R + lro;
      int gc = (cl ^ (gr & 7)) * 8;
      gl_lds16(&Vp[(size_t)gr * SEQ + s0 + gc], &sVt[R * 128]);
    }
    __syncthreads();

    // S^T: A=K rows (kv), B=Q rows (q). D[kv=j*16+quad*4+r][q=lr]
    f32x4 st_[8];
    #pragma unroll
    for (int j = 0; j < 8; j++) st_[j] = (f32x4){0.f,0.f,0.f,0.f};
    #pragma unroll
    for (int ks = 0; ks < 2; ks++){
      #pragma unroll
      for (int j = 0; j < 8; j++){
        short8 kf = *(const short8*)&sK[(j*16 + lr)*64 + (((ks*4 + quad) ^ (lr & 7)) * 8)];
        st_[j] = MFMA16(kf, qf[ks], st_[j]);
      }
    }

    // P = 2^(S^T), pack pairs, b64 to swizzled sP[q=lr][kv]
    #pragma unroll
    for (int j = 0; j < 8; j++){
      float p0 = __builtin_amdgcn_exp2f(st_[j][0]);
      float p1 = __builtin_amdgcn_exp2f(st_[j][1]);
      float p2 = __builtin_amdgcn_exp2f(st_[j][2]);
      float p3 = __builtin_amdgcn_exp2f(st_[j][3]);
      uint2 pv; pv.x = pk_bf16(p0, p1); pv.y = pk_bf16(p2, p3);
      int c = j*2 + (quad >> 1);
      *(uint2*)&sP[w*2048 + lr*128 + ((c ^ (lr & 7)) * 8) + (quad & 1)*4] = pv;
    }

    // PV + l: A=P rows (q), B=Vt rows (d) / ones
    #pragma unroll
    for (int ks = 0; ks < 4; ks++){
      short8 pf = *(const short8*)&sP[w*2048 + lr*128 + (((ks*4 + quad) ^ (lr & 7)) * 8)];
      accl = MFMA16(pf, ones, accl);
      #pragma unroll
      for (int jc = 0; jc < 4; jc++){
        short8 vf = *(const short8*)&sVt[(jc*16 + lr)*128 + (((ks*4 + quad) ^ (lr & 7)) * 8)];
        acco[jc] = MFMA16(pf, vf, acco[jc]);
      }
    }
  }

  // epilogue: normalize by l, scatter to [B,S,H*dk]
  const int bq = bh >> 4, hh = bh & 15;
  u16* op = ctx + ((size_t)bq * SEQ + q0) * D_MODEL + hh * DKH;
  #pragma unroll
  for (int r = 0; r < 4; r++){
    float rl = 1.f / accl[r];
    int row = w*16 + quad*4 + r;
    #pragma unroll
    for (int jc = 0; jc < 4; jc++)
      op[(size_t)row * D_MODEL + jc*16 + lr] = f2b(acco[jc][r] * rl);
  }
}

// ---------------------------------------------------------------------------
extern "C" void kernel_launch(void* const* d_in, const int* in_sizes, int n_in,
                              void* d_out, int out_size, void* d_ws, size_t ws_size,
                              hipStream_t stream)
{
  const float* x   = (const float*)d_in[0];
  const float* Wq  = (const float*)d_in[1];
  const float* bq  = (const float*)d_in[2];
  const float* Wk  = (const float*)d_in[3];
  const float* bk  = (const float*)d_in[4];
  const float* Wv  = (const float*)d_in[5];
  const float* bv  = (const float*)d_in[6];
  const float* Wo  = (const float*)d_in[7];
  const float* bo  = (const float*)d_in[8];
  const float* W1  = (const float*)d_in[9];
  const float* b1  = (const float*)d_in[10];
  const float* W2  = (const float*)d_in[11];
  const float* b2  = (const float*)d_in[12];
  const float* g1  = (const float*)d_in[13];
  const float* be1 = (const float*)d_in[14];
  const float* g2  = (const float*)d_in[15];
  const float* be2 = (const float*)d_in[16];

  char* ws = (char*)d_ws;
  const size_t MB = 1024ull * 1024ull;
  u16* wqb = (u16*)(ws + 0*MB);
  u16* wkb = (u16*)(ws + 2*MB);
  u16* wvb = (u16*)(ws + 4*MB);
  u16* wob = (u16*)(ws + 6*MB);
  u16* w1b = (u16*)(ws + 8*MB);    // 8 MB (4096x1024)
  u16* w2b = (u16*)(ws + 16*MB);   // 8 MB (1024x4096)
  u16* h   = (u16*)(ws + 24*MB);   // bf16 activations; reused as h2
  u16* q   = (u16*)(ws + 32*MB);   // [B,H,S,dk]
  u16* k   = (u16*)(ws + 40*MB);
  u16* ctx = (u16*)(ws + 48*MB);   // attn output
  u16* vt  = (u16*)(ws + 56*MB);   // [B,H,dk,S] — written by gemm_qkv z==2
  u16* ff  = (u16*)(ws + 32*MB);   // 32 MB [M,D_FF]; q/k/ctx/vt dead by then
  u16* h2  = h;
  float* x1 = (float*)d_out;       // attn residual output (fp32) in d_out

  // 0. weights -> bf16 + LN1 fused (7th y-slice)
  cvt_ln_kernel<<<dim3(4096, 7), 256, 0, stream>>>(
      Wq, Wk, Wv, Wo, W1, W2, wqb, wkb, wvb, wob, w1b, w2b,
      x, g1, be1, h);

  // 1. QKV projections (128x128, wave 64x64); V written transposed to vt
  gemm_qkv<<<dim3(M_TOK/128, D_MODEL/128, 3), 256, 0, stream>>>(
      h, wqb, bq, wkb, bk, wvb, bv, q, k, vt);
  // 2. flash attention (512 threads, 8 waves)
  attn_kernel<<<dim3(BATCH*N_HEADS, SEQ/128), 512, 0, stream>>>(q, k, vt, ctx);
  // 3. Wo + residual(x) -> x1 fp32; single-buf 64x128 BK=128 (proven)
  gemm_wo<<<dim3(M_TOK/64, D_MODEL/128), 256, 0, stream>>>(
      ctx, wob, bo, x, (void*)x1);
  // 4. LN2 (fp32 x1 -> bf16 h2)
  ln_kernel<<<M_TOK, 256, 0, stream>>>(x1, g2, be2, h2);
  // 5. FF1 + GELU -> bf16 ff; 128x128 BK=64 single-buf
  gemm_ff1<<<dim3(M_TOK/128, D_FF/128), 256, 0, stream>>>(
      h2, w1b, b1, (void*)ff);
  // 6. FF2 + residual(x1) -> d_out fp32; single-buf 64x128 BK=128 (proven 54us)
  gemm_ff2<<<dim3(M_TOK/64, D_MODEL/128), 256, 0, stream>>>(
      ff, w2b, b2, x1, d_out);
}